// Round 1
// baseline (962.891 us; speedup 1.0000x reference)
//
#include <hip/hip_runtime.h>
#include <cstdint>
#include <cstddef>

// ---------------------------------------------------------------------------
// DynamicReflectionAttention fused pipeline for MI355X (gfx950)
// Layouts: all intermediate activations are PIXEL-MAJOR fp16:
//   X[(b*HW + p)][channel], row stride = channel count.
// GEMMs: C[pixel][outch] = sum_k X[pixel][k] * W[outch][k]  (MFMA 16x16x32 f16)
// ---------------------------------------------------------------------------

typedef _Float16 f16;
using half8  = __attribute__((ext_vector_type(8))) _Float16;
using float4v = __attribute__((ext_vector_type(4))) float;

#define HW    16384
#define NPIX  32768

union U4H8 { uint4 u; f16 h[8]; };
union U2H4 { uint2 u; f16 h[4]; };

// ---------------- weight fp32 -> fp16 convert (7 tensors, one launch) -------
struct WConvArgs { const float* src[7]; f16* dst[7]; int n[7]; };
__global__ __launch_bounds__(256) void wconv_kernel(WConvArgs a) {
  int t = blockIdx.y;
  const float* s = a.src[t]; f16* d = a.dst[t]; int n = a.n[t];
  for (int i = blockIdx.x * 256 + threadIdx.x; i < n; i += gridDim.x * 256)
    d[i] = (f16)s[i];
}

// ---------------- cnorm of NCHW fp32 input -> pixel-major f16 Fcat ----------
// grid.x = NPIX/64 ; block 256. Fcat rows are 384 wide: [Frn | Fyn]
__global__ __launch_bounds__(256) void cnorm_in_kernel(const float* __restrict__ x,
                                                       f16* __restrict__ fcat, int zoff) {
  __shared__ float tile[64][193];
  __shared__ float rsum[64][4], rsq[64][4], mm[64], rr[64];
  int tid = threadIdx.x;
  int P0 = blockIdx.x * 64;
  int b  = P0 >> 14;
  int p0 = P0 & (HW - 1);
  for (int i = tid; i < 64 * 192; i += 256) {
    int c = i >> 6, pp = i & 63;                       // coalesced over pixels
    tile[pp][c] = x[((size_t)(b * 192 + c)) * HW + p0 + pp];
  }
  __syncthreads();
  {
    int pp = tid >> 2, q = tid & 3;
    float s = 0.f, s2 = 0.f;
    for (int c = q * 48; c < q * 48 + 48; c++) { float v = tile[pp][c]; s += v; s2 += v * v; }
    rsum[pp][q] = s; rsq[pp][q] = s2;
  }
  __syncthreads();
  if (tid < 64) {
    float s  = rsum[tid][0] + rsum[tid][1] + rsum[tid][2] + rsum[tid][3];
    float s2 = rsq[tid][0] + rsq[tid][1] + rsq[tid][2] + rsq[tid][3];
    float mu = s * (1.f / 192.f);
    float var = s2 * (1.f / 192.f) - mu * mu;
    mm[tid] = mu; rr[tid] = rsqrtf(var + 1e-5f);
  }
  __syncthreads();
  for (int i = tid; i < 64 * 192; i += 256) {
    int pp = i / 192, c = i - pp * 192;                // c fast -> coalesced write
    float v = (tile[pp][c] - mm[pp]) * rr[pp];
    fcat[(size_t)(P0 + pp) * 384 + zoff + c] = (f16)v;
  }
}

// ---------------- cnorm of pixel-major fp32 -> pixel-major f16 --------------
__global__ __launch_bounds__(256) void norm_pm_kernel(const float* __restrict__ xpm,
                                                      f16* __restrict__ outn) {
  __shared__ float tile[64][193];
  __shared__ float rsum[64][4], rsq[64][4], mm[64], rr[64];
  int tid = threadIdx.x;
  int P0 = blockIdx.x * 64;
  for (int i = tid; i < 64 * 192; i += 256) {
    int pp = i / 192, c = i - pp * 192;
    tile[pp][c] = xpm[(size_t)(P0 + pp) * 192 + c];
  }
  __syncthreads();
  {
    int pp = tid >> 2, q = tid & 3;
    float s = 0.f, s2 = 0.f;
    for (int c = q * 48; c < q * 48 + 48; c++) { float v = tile[pp][c]; s += v; s2 += v * v; }
    rsum[pp][q] = s; rsq[pp][q] = s2;
  }
  __syncthreads();
  if (tid < 64) {
    float s  = rsum[tid][0] + rsum[tid][1] + rsum[tid][2] + rsum[tid][3];
    float s2 = rsq[tid][0] + rsq[tid][1] + rsq[tid][2] + rsq[tid][3];
    float mu = s * (1.f / 192.f);
    float var = s2 * (1.f / 192.f) - mu * mu;
    mm[tid] = mu; rr[tid] = rsqrtf(var + 1e-5f);
  }
  __syncthreads();
  for (int i = tid; i < 64 * 192; i += 256) {
    int pp = i / 192, c = i - pp * 192;
    outn[(size_t)(P0 + pp) * 192 + c] = (f16)((tile[pp][c] - mm[pp]) * rr[pp]);
  }
}

// ---------------- generic 128x128x32 MFMA GEMM with epilogue modes ----------
// MODE 0: plain f16 store        (qkv, pin)
// MODE 1: gelu + w_g2 row-reduction into alpha_acc atomics (g1 gemm, no store)
// MODE 2: A = [alpha*v_raw ; (1-alpha)*v_rgb]; epi: +b_fc +Frn +Fyn -> fp32 outpm
// MODE 3: epi: + outpm residual, LDS-transpose, store NCHW fp32 d_out (pout)
struct GArgs {
  const f16* A; long lda; long aoff;
  const f16* B1; const f16* B2; int b1rows; int Nout; int K; long bStride;
  f16* outH; long ldo;
  const float* bfc; const f16* fcat; float* outpm;
  const float* bg1; const float* wg2; float* alpha_acc;
  const f16* vraw; const f16* vrgb; const float* alpha_pre; const float* bg2;
  const float* outpm_r; float* dout;
};

template <int MODE>
__global__ __launch_bounds__(256) void gemm_k(GArgs g) {
  __shared__ __align__(16) char smem[21504];
  f16 (*As)[40] = (f16(*)[40])smem;            // 128 x (32+8) f16 = 10240 B
  f16 (*Bs)[40] = (f16(*)[40])(smem + 10240);  // 10240 B
  float* salpha = (float*)(smem + 20480);      // 512 B (MODE 2)

  int tid = threadIdx.x;
  int P0 = blockIdx.y * 128;
  int n0 = blockIdx.x * 128;
  int wave = tid >> 6, lane = tid & 63, l15 = lane & 15, quad = lane >> 4;
  int m_off = (wave >> 1) * 64, n_off = (wave & 1) * 64;
  const f16* B1 = g.B1 + (size_t)(P0 >> 14) * g.bStride;

  if (MODE == 2) {
    if (tid < 128) {
      float a = g.alpha_pre[P0 + tid] + g.bg2[0];
      salpha[tid] = 1.f / (1.f + __expf(-a));
    }
  }
  __syncthreads();

  float4v acc[4][4];
#pragma unroll
  for (int i = 0; i < 4; i++)
#pragma unroll
    for (int j = 0; j < 4; j++) acc[i][j] = (float4v){0.f, 0.f, 0.f, 0.f};

  int srow = tid >> 2;
  int scc  = (tid & 3) * 8;

  for (int k0 = 0; k0 < g.K; k0 += 32) {
    uint4 av[2], bv[2];
#pragma unroll
    for (int h = 0; h < 2; h++) {
      int row = srow + h * 64;
      if (MODE == 2) {
        int k = k0 + scc;
        const f16* src = (k < 192) ? (g.vraw + (size_t)(P0 + row) * 576 + 192 + k)
                                   : (g.vrgb + (size_t)(P0 + row) * 576 + k);
        float s = (k < 192) ? salpha[row] : (1.f - salpha[row]);
        U4H8 t; t.u = *(const uint4*)src;
#pragma unroll
        for (int e = 0; e < 8; e++) t.h[e] = (f16)((float)t.h[e] * s);
        av[h] = t.u;
      } else {
        av[h] = *(const uint4*)(g.A + (size_t)(P0 + row) * g.lda + g.aoff + k0 + scc);
      }
      int n = n0 + row;
      uint4 bb = {0u, 0u, 0u, 0u};
      if (n < g.b1rows)      bb = *(const uint4*)(B1 + (size_t)n * g.K + k0 + scc);
      else if (n < g.Nout)   bb = *(const uint4*)(g.B2 + (size_t)(n - g.b1rows) * g.K + k0 + scc);
      bv[h] = bb;
    }
    __syncthreads();   // previous tile consumed
#pragma unroll
    for (int h = 0; h < 2; h++) {
      *(uint4*)&As[srow + h * 64][scc] = av[h];
      *(uint4*)&Bs[srow + h * 64][scc] = bv[h];
    }
    __syncthreads();
    half8 af[4], bf[4];
#pragma unroll
    for (int i = 0; i < 4; i++) af[i] = *(const half8*)&As[m_off + i * 16 + l15][quad * 8];
#pragma unroll
    for (int i = 0; i < 4; i++) bf[i] = *(const half8*)&Bs[n_off + i * 16 + l15][quad * 8];
#pragma unroll
    for (int mi = 0; mi < 4; mi++)
#pragma unroll
      for (int ni = 0; ni < 4; ni++)
        acc[mi][ni] = __builtin_amdgcn_mfma_f32_16x16x32_f16(af[mi], bf[ni], acc[mi][ni], 0, 0, 0);
  }

  if (MODE == 0) {
#pragma unroll
    for (int mi = 0; mi < 4; mi++) {
      int row = P0 + m_off + mi * 16 + quad * 4;
#pragma unroll
      for (int ni = 0; ni < 4; ni++) {
        int gcol = n0 + n_off + ni * 16 + l15;
        if (gcol < g.Nout) {
#pragma unroll
          for (int r = 0; r < 4; r++)
            g.outH[(size_t)(row + r) * g.ldo + gcol] = (f16)acc[mi][ni][r];
        }
      }
    }
  } else if (MODE == 1) {
    float bg[4], wg[4];
#pragma unroll
    for (int ni = 0; ni < 4; ni++) {
      int gcol = n0 + n_off + ni * 16 + l15;
      bg[ni] = g.bg1[gcol]; wg[ni] = g.wg2[gcol];
    }
    float psum[4][4];
#pragma unroll
    for (int mi = 0; mi < 4; mi++)
#pragma unroll
      for (int r = 0; r < 4; r++) psum[mi][r] = 0.f;
#pragma unroll
    for (int mi = 0; mi < 4; mi++)
#pragma unroll
      for (int ni = 0; ni < 4; ni++)
#pragma unroll
        for (int r = 0; r < 4; r++) {
          float xx = acc[mi][ni][r] + bg[ni];
          float ge = 0.5f * xx * (1.f + erff(xx * 0.70710678118f));
          psum[mi][r] += ge * wg[ni];
        }
#pragma unroll
    for (int s = 1; s < 16; s <<= 1)
#pragma unroll
      for (int mi = 0; mi < 4; mi++)
#pragma unroll
        for (int r = 0; r < 4; r++) psum[mi][r] += __shfl_xor(psum[mi][r], s, 64);
    if (l15 == 0) {
#pragma unroll
      for (int mi = 0; mi < 4; mi++)
#pragma unroll
        for (int r = 0; r < 4; r++)
          atomicAdd(&g.alpha_acc[P0 + m_off + mi * 16 + quad * 4 + r], psum[mi][r]);
    }
  } else if (MODE == 2) {
#pragma unroll
    for (int mi = 0; mi < 4; mi++) {
      int prow = P0 + m_off + mi * 16 + quad * 4;
#pragma unroll
      for (int ni = 0; ni < 4; ni++) {
        int gcol = n0 + n_off + ni * 16 + l15;
        if (gcol < 192) {
#pragma unroll
          for (int r = 0; r < 4; r++) {
            size_t P = (size_t)(prow + r);
            float v = acc[mi][ni][r] + g.bfc[gcol] +
                      (float)g.fcat[P * 384 + gcol] + (float)g.fcat[P * 384 + 192 + gcol];
            g.outpm[P * 192 + gcol] = v;
          }
        }
      }
    }
  } else {  // MODE 3
#pragma unroll
    for (int mi = 0; mi < 4; mi++) {
      int prow = P0 + m_off + mi * 16 + quad * 4;
#pragma unroll
      for (int ni = 0; ni < 4; ni++) {
        int gcol = n0 + n_off + ni * 16 + l15;
        if (gcol < 192) {
#pragma unroll
          for (int r = 0; r < 4; r++)
            acc[mi][ni][r] += g.outpm_r[(size_t)(prow + r) * 192 + gcol];
        }
      }
    }
    float (*bounce)[129] = (float(*)[129])smem;  // 32 x 129 fp32 = 16512 B
    for (int cg = 0; cg < 4; cg++) {
      __syncthreads();
      if ((wave & 1) == (cg >> 1)) {
#pragma unroll
        for (int nn = 0; nn < 2; nn++) {
          int ni = (cg & 1) * 2 + nn;
          int lc = nn * 16 + l15;
#pragma unroll
          for (int mi = 0; mi < 4; mi++)
#pragma unroll
            for (int r = 0; r < 4; r++)
              bounce[lc][m_off + mi * 16 + quad * 4 + r] = acc[mi][ni][r];
        }
      }
      __syncthreads();
      int c = tid >> 3, ps = (tid & 7) * 16;
      int gc = n0 + cg * 32 + c;
      if (gc < 192) {
        int b = P0 >> 14, p = (P0 & (HW - 1)) + ps;
        float* dst = g.dout + ((size_t)b * 192 + gc) * HW + p;
#pragma unroll
        for (int i = 0; i < 16; i++) dst[i] = bounce[c][ps + i];
      }
    }
  }
}

// ---------------- split-K Gram + sum-of-squares for attention ---------------
// grid (128 pixel-chunks, 4 heads, 2 batch). qkv rows: [k|v|q], 576 wide.
// gram layout per (b,h): [G1 2304 | G2 2304 | nsq 4*48]  (fp32, atomically built)
__global__ __launch_bounds__(256) void gram_kernel(const f16* __restrict__ qkvR,
                                                   const f16* __restrict__ qkvG,
                                                   float* __restrict__ gram) {
  __shared__ f16 gq[4][128][48];
  int tid = threadIdx.x;
  int chunk = blockIdx.x, h = blockIdx.y, b = blockIdx.z;
  size_t rowbase = ((size_t)b * HW + (size_t)chunk * 128) * 576;
  int colq = 384 + 48 * h, colk = 48 * h;
  for (int ii = tid; ii < 3072; ii += 256) {
    int tt = ii / 768, rem = ii - tt * 768;
    int pp = rem / 6, c6 = (rem - pp * 6) * 8;
    const f16* src; int col;
    if (tt == 0)      { src = qkvG; col = colq; }   // q_rgb
    else if (tt == 1) { src = qkvR; col = colk; }   // k_raw
    else if (tt == 2) { src = qkvR; col = colq; }   // q_raw
    else              { src = qkvG; col = colk; }   // k_rgb
    uint4 v = *(const uint4*)(src + rowbase + (size_t)pp * 576 + col + c6);
    *(uint4*)&gq[tt][pp][c6] = v;
  }
  __syncthreads();
  int cg = (tid >> 4) * 3, dg = (tid & 15) * 3;
  float A1[3][3], A2[3][3];
#pragma unroll
  for (int i = 0; i < 3; i++)
#pragma unroll
    for (int j = 0; j < 3; j++) { A1[i][j] = 0.f; A2[i][j] = 0.f; }
  int ntn = tid / 48, nch = tid - ntn * 48;
  float ns = 0.f;
  for (int pp = 0; pp < 128; pp++) {
    float qr[3], kr[3], qa[3], kb[3];
#pragma unroll
    for (int i = 0; i < 3; i++) {
      qr[i] = (float)gq[0][pp][cg + i];
      kr[i] = (float)gq[1][pp][dg + i];
      qa[i] = (float)gq[2][pp][cg + i];
      kb[i] = (float)gq[3][pp][dg + i];
    }
#pragma unroll
    for (int i = 0; i < 3; i++)
#pragma unroll
      for (int j = 0; j < 3; j++) { A1[i][j] += qr[i] * kr[j]; A2[i][j] += qa[i] * kb[j]; }
    if (tid < 192) { float v = (float)gq[ntn][pp][nch]; ns += v * v; }
  }
  float* base = gram + ((size_t)b * 4 + h) * 4800;
#pragma unroll
  for (int i = 0; i < 3; i++)
#pragma unroll
    for (int j = 0; j < 3; j++) {
      atomicAdd(base + (cg + i) * 48 + dg + j, A1[i][j]);
      atomicAdd(base + 2304 + (cg + i) * 48 + dg + j, A2[i][j]);
    }
  if (tid < 192) atomicAdd(base + 4608 + tid, ns);
}

// ---------------- softmax over 48 cols of 16 tiny matrices ------------------
__global__ void softmax_kernel(const float* __restrict__ gram, const float* __restrict__ temp,
                               float* __restrict__ att) {
  int id = blockIdx.x;                    // 16 = b*8 + h*2 + pr
  int b = id >> 3, h = (id >> 1) & 3, pr = id & 1;
  int tid = threadIdx.x;                  // 64
  __shared__ float srk[48];
  const float* base = gram + ((size_t)b * 4 + h) * 4800;
  const float* G  = base + pr * 2304;
  const float* nq = base + 4608 + (pr ? 96 : 0);
  const float* nk = base + 4608 + (pr ? 144 : 48);
  if (tid < 48) srk[tid] = 1.f / fmaxf(sqrtf(nk[tid]), 1e-12f);
  __syncthreads();
  if (tid < 48) {
    float rq = 1.f / fmaxf(sqrtf(nq[tid]), 1e-12f);
    float T = temp[h];
    float s[48], mx = -1e30f;
#pragma unroll
    for (int d = 0; d < 48; d++) { s[d] = T * G[tid * 48 + d] * rq * srk[d]; mx = fmaxf(mx, s[d]); }
    float sum = 0.f;
#pragma unroll
    for (int d = 0; d < 48; d++) { s[d] = __expf(s[d] - mx); sum += s[d]; }
    float inv = 1.f / sum;
    float* A = att + (((size_t)b * 2 + pr) * 4 + h) * 2304 + tid * 48;
#pragma unroll
    for (int d = 0; d < 48; d++) A[d] = s[d] * inv;
  }
}

// ---------------- M_cat = [W_fc*blkdiag(A_raw) | W_fc*blkdiag(A_rgb)] -------
__global__ __launch_bounds__(256) void mbuild_kernel(const float* __restrict__ wfc,
                                                     const float* __restrict__ att,
                                                     f16* __restrict__ mcat) {
  int e = blockIdx.x * 256 + threadIdx.x;
  if (e >= 147456) return;
  int b = e / 73728, r = e - b * 73728;
  int o = r / 384, j = r - o * 384;
  int pr = j / 192, jj = j - pr * 192;
  int h = jj / 48, d = jj - h * 48;
  const float* A = att + (((size_t)b * 2 + pr) * 4 + h) * 2304 + d;
  const float* w = wfc + o * 192 + h * 48;
  float s = 0.f;
  for (int c = 0; c < 48; c++) s += w[c] * A[c * 48];
  mcat[(size_t)b * 73728 + o * 384 + j] = (f16)s;
}

// ---------------- fused pshuffle -> dwconv5x5 & dil-3x3 -> mish -> punshuffle
// hid: pixel-major 1024 f16. u: pixel-major 512 f16.
// grid: (64 spatial tiles 16x16, 128 channel-groups, 2 batch)
__global__ __launch_bounds__(256) void dwmish_kernel(const f16* __restrict__ hid,
                                                     const float* __restrict__ w5,
                                                     const float* __restrict__ w3,
                                                     f16* __restrict__ u) {
  __shared__ f16 sx[324][8];   // 18x18 pixels x (4 x1-subch + 4 x2-subch)
  __shared__ float sw5[25], sw3[9];
  int tid = threadIdx.x;
  int c = blockIdx.y, b = blockIdx.z;
  int ti0 = (blockIdx.x >> 3) * 16, tj0 = (blockIdx.x & 7) * 16;
  if (tid < 25) sw5[tid] = w5[c * 25 + tid];
  if (tid >= 32 && tid < 41) sw3[tid - 32] = w3[c * 9 + tid - 32];
  for (int ii = tid; ii < 648; ii += 256) {
    int pix = ii >> 1, half = ii & 1;
    int pi = pix / 18, pj = pix - pi * 18;
    int gi = ti0 - 1 + pi, gj = tj0 - 1 + pj;
    uint2 v = {0u, 0u};
    if (gi >= 0 && gi < 128 && gj >= 0 && gj < 128)
      v = *(const uint2*)(hid + ((size_t)b * HW + gi * 128 + gj) * 1024 + half * 512 + c * 4);
    *(uint2*)&sx[pix][half * 4] = v;
  }
  __syncthreads();
  int ti = tid >> 4, tj = tid & 15;
  int gi = ti0 + ti, gj = tj0 + tj;
  U2H4 res;
#pragma unroll
  for (int pq = 0; pq < 4; pq++) {
    int p = pq >> 1, q = pq & 1;
    float a2 = 0.f;
#pragma unroll
    for (int ky = 0; ky < 3; ky++)
#pragma unroll
      for (int kx = 0; kx < 3; kx++)
        a2 += sw3[ky * 3 + kx] * (float)sx[(ti + ky) * 18 + tj + kx][4 + pq];
    float a1 = 0.f;
#pragma unroll
    for (int dy = -2; dy <= 2; dy++)
#pragma unroll
      for (int dx = -2; dx <= 2; dx++) {
        int s = p + dy, t2 = q + dx;
        int di = s >> 1, ps_ = s & 1;
        int dj = t2 >> 1, qs_ = t2 & 1;
        a1 += sw5[(dy + 2) * 5 + dx + 2] * (float)sx[(ti + 1 + di) * 18 + tj + 1 + dj][ps_ * 2 + qs_];
      }
    float sp = (a2 > 15.f) ? a2 : log1pf(__expf(a2));
    res.h[pq] = (f16)(a2 * tanhf(sp) * a1);
  }
  *(uint2*)(u + ((size_t)b * HW + gi * 128 + gj) * 512 + c * 4) = res.u;
}

// ---------------------------------------------------------------------------
extern "C" void kernel_launch(void* const* d_in, const int* in_sizes, int n_in,
                              void* d_out, int out_size, void* d_ws, size_t ws_size,
                              hipStream_t stream) {
  const float* F_raw    = (const float*)d_in[0];
  const float* F_Y      = (const float*)d_in[1];
  const float* temp     = (const float*)d_in[2];
  const float* w_raw_kv = (const float*)d_in[3];
  const float* w_raw_q  = (const float*)d_in[4];
  const float* w_rgb_kv = (const float*)d_in[5];
  const float* w_rgb_q  = (const float*)d_in[6];
  const float* w_g1     = (const float*)d_in[7];
  const float* b_g1     = (const float*)d_in[8];
  const float* w_g2     = (const float*)d_in[9];
  const float* b_g2     = (const float*)d_in[10];
  const float* w_fc     = (const float*)d_in[11];
  const float* b_fc     = (const float*)d_in[12];
  const float* w_pin    = (const float*)d_in[13];
  const float* w_dw5    = (const float*)d_in[14];
  const float* w_dwd    = (const float*)d_in[15];
  const float* w_pout   = (const float*)d_in[16];
  char* ws = (char*)d_ws;
  float* dout = (float*)d_out;

  const size_t O_FCAT  = 0;            // 25,165,824  f16 Fcat (NPIX x 384)
  const size_t O_QKV0  = 25165824;     // 37,748,736  f16 raw [k|v|q] (NPIX x 576)
  const size_t O_QKV1  = 62914560;     // 37,748,736  f16 rgb
  const size_t O_ALPHA = 100663296;    // 131,072     fp32 alpha pre-sigmoid
  const size_t O_GRAM  = 100794368;    // 153,600     fp32 grams+normsq
  const size_t O_ATT   = 100947968;    // 147,456     fp32 softmaxed attn
  const size_t O_MCAT  = 101095424;    // 294,912     f16 M_cat (2 x 192 x 384)
  const size_t O_WB    = 101390336;    // 1,622,016   f16 converted weights
  const size_t O_OUTPM = 103012352;    // 25,165,824  fp32 out pixel-major
  const size_t O_NORM  = 128178176;    // 12,582,912  f16 cnorm(out)
  const size_t O_HID   = O_QKV0;       // 67,108,864  f16 hidden (reuses dead qkv)
  const size_t O_U     = 140761088;    // 33,554,432  f16 u  (ends 174,315,520)
  if (ws_size < 174315520) return;

  f16* wb      = (f16*)(ws + O_WB);
  f16* wb_kvR  = wb;
  f16* wb_qR   = wb + 73728;
  f16* wb_kvG  = wb + 110592;
  f16* wb_qG   = wb + 184320;
  f16* wb_g1   = wb + 221184;
  f16* wb_pin  = wb + 516096;
  f16* wb_pout = wb + 712704;

  WConvArgs wa;
  wa.src[0] = w_raw_kv; wa.dst[0] = wb_kvR;  wa.n[0] = 73728;
  wa.src[1] = w_raw_q;  wa.dst[1] = wb_qR;   wa.n[1] = 36864;
  wa.src[2] = w_rgb_kv; wa.dst[2] = wb_kvG;  wa.n[2] = 73728;
  wa.src[3] = w_rgb_q;  wa.dst[3] = wb_qG;   wa.n[3] = 36864;
  wa.src[4] = w_g1;     wa.dst[4] = wb_g1;   wa.n[4] = 294912;
  wa.src[5] = w_pin;    wa.dst[5] = wb_pin;  wa.n[5] = 196608;
  wa.src[6] = w_pout;   wa.dst[6] = wb_pout; wa.n[6] = 98304;
  wconv_kernel<<<dim3(16, 7), 256, 0, stream>>>(wa);

  hipMemsetAsync(ws + O_ALPHA, 0, 131072 + 153600, stream);

  f16* fcat = (f16*)(ws + O_FCAT);
  cnorm_in_kernel<<<512, 256, 0, stream>>>(F_raw, fcat, 0);
  cnorm_in_kernel<<<512, 256, 0, stream>>>(F_Y, fcat, 192);

  {  // qkv raw + rgb
    GArgs a = {};
    a.A = fcat; a.lda = 384; a.aoff = 0;
    a.B1 = wb_kvR; a.B2 = wb_qR; a.b1rows = 384; a.Nout = 576; a.K = 192; a.bStride = 0;
    a.outH = (f16*)(ws + O_QKV0); a.ldo = 576;
    gemm_k<0><<<dim3(5, 256), 256, 0, stream>>>(a);
    a.aoff = 192; a.B1 = wb_kvG; a.B2 = wb_qG; a.outH = (f16*)(ws + O_QKV1);
    gemm_k<0><<<dim3(5, 256), 256, 0, stream>>>(a);
  }
  {  // g1 gemm with gelu + alpha row-reduction
    GArgs a = {};
    a.A = fcat; a.lda = 384; a.aoff = 0;
    a.B1 = wb_g1; a.B2 = wb_g1; a.b1rows = 768; a.Nout = 768; a.K = 384; a.bStride = 0;
    a.bg1 = b_g1; a.wg2 = w_g2; a.alpha_acc = (float*)(ws + O_ALPHA);
    gemm_k<1><<<dim3(6, 256), 256, 0, stream>>>(a);
  }
  gram_kernel<<<dim3(128, 4, 2), 256, 0, stream>>>((const f16*)(ws + O_QKV0),
                                                   (const f16*)(ws + O_QKV1),
                                                   (float*)(ws + O_GRAM));
  softmax_kernel<<<16, 64, 0, stream>>>((const float*)(ws + O_GRAM), temp, (float*)(ws + O_ATT));
  mbuild_kernel<<<576, 256, 0, stream>>>(w_fc, (const float*)(ws + O_ATT), (f16*)(ws + O_MCAT));
  {  // ctx + fc + residual -> outpm fp32
    GArgs a = {};
    a.B1 = (const f16*)(ws + O_MCAT); a.B2 = (const f16*)(ws + O_MCAT);
    a.b1rows = 192; a.Nout = 192; a.K = 384; a.bStride = 73728;
    a.vraw = (const f16*)(ws + O_QKV0); a.vrgb = (const f16*)(ws + O_QKV1);
    a.alpha_pre = (float*)(ws + O_ALPHA); a.bg2 = b_g2;
    a.bfc = b_fc; a.fcat = fcat; a.outpm = (float*)(ws + O_OUTPM);
    gemm_k<2><<<dim3(2, 256), 256, 0, stream>>>(a);
  }
  norm_pm_kernel<<<512, 256, 0, stream>>>((const float*)(ws + O_OUTPM), (f16*)(ws + O_NORM));
  {  // pin gemm -> hidden
    GArgs a = {};
    a.A = (const f16*)(ws + O_NORM); a.lda = 192; a.aoff = 0;
    a.B1 = wb_pin; a.B2 = wb_pin; a.b1rows = 1024; a.Nout = 1024; a.K = 192; a.bStride = 0;
    a.outH = (f16*)(ws + O_HID); a.ldo = 1024;
    gemm_k<0><<<dim3(8, 256), 256, 0, stream>>>(a);
  }
  dwmish_kernel<<<dim3(64, 128, 2), 256, 0, stream>>>((const f16*)(ws + O_HID), w_dw5, w_dwd,
                                                      (f16*)(ws + O_U));
  {  // pout gemm + residual -> d_out (NCHW fp32)
    GArgs a = {};
    a.A = (const f16*)(ws + O_U); a.lda = 512; a.aoff = 0;
    a.B1 = wb_pout; a.B2 = wb_pout; a.b1rows = 192; a.Nout = 192; a.K = 512; a.bStride = 0;
    a.outpm_r = (const float*)(ws + O_OUTPM); a.dout = dout;
    gemm_k<3><<<dim3(2, 256), 256, 0, stream>>>(a);
  }
}

// Round 2
// 751.575 us; speedup vs baseline: 1.2812x; 1.2812x over previous
//
#include <hip/hip_runtime.h>
#include <cstdint>
#include <cstddef>

// ---------------------------------------------------------------------------
// DynamicReflectionAttention fused pipeline for MI355X (gfx950)
// Layouts: all intermediate activations are PIXEL-MAJOR fp16:
//   X[(b*HW + p)][channel], row stride = channel count.
// GEMMs: C[pixel][outch] = sum_k X[pixel][k] * W[outch][k]  (MFMA 16x16x32 f16)
// ---------------------------------------------------------------------------

typedef _Float16 f16;
using half8  = __attribute__((ext_vector_type(8))) _Float16;
using float4v = __attribute__((ext_vector_type(4))) float;

#define HW    16384
#define NPIX  32768

union U4H8 { uint4 u; f16 h[8]; };
union U2H4 { uint2 u; f16 h[4]; };

// ---------------- weight fp32 -> fp16 convert (7 tensors, one launch) -------
struct WConvArgs { const float* src[7]; f16* dst[7]; int n[7]; };
__global__ __launch_bounds__(256) void wconv_kernel(WConvArgs a) {
  int t = blockIdx.y;
  const float* s = a.src[t]; f16* d = a.dst[t]; int n = a.n[t];
  for (int i = blockIdx.x * 256 + threadIdx.x; i < n; i += gridDim.x * 256)
    d[i] = (f16)s[i];
}

// ---------------- cnorm of NCHW fp32 input -> pixel-major f16 Fcat ----------
__global__ __launch_bounds__(256) void cnorm_in_kernel(const float* __restrict__ x,
                                                       f16* __restrict__ fcat, int zoff) {
  __shared__ float tile[64][193];
  __shared__ float rsum[64][4], rsq[64][4], mm[64], rr[64];
  int tid = threadIdx.x;
  int P0 = blockIdx.x * 64;
  int b  = P0 >> 14;
  int p0 = P0 & (HW - 1);
  for (int i = tid; i < 64 * 192; i += 256) {
    int c = i >> 6, pp = i & 63;
    tile[pp][c] = x[((size_t)(b * 192 + c)) * HW + p0 + pp];
  }
  __syncthreads();
  {
    int pp = tid >> 2, q = tid & 3;
    float s = 0.f, s2 = 0.f;
    for (int c = q * 48; c < q * 48 + 48; c++) { float v = tile[pp][c]; s += v; s2 += v * v; }
    rsum[pp][q] = s; rsq[pp][q] = s2;
  }
  __syncthreads();
  if (tid < 64) {
    float s  = rsum[tid][0] + rsum[tid][1] + rsum[tid][2] + rsum[tid][3];
    float s2 = rsq[tid][0] + rsq[tid][1] + rsq[tid][2] + rsq[tid][3];
    float mu = s * (1.f / 192.f);
    float var = s2 * (1.f / 192.f) - mu * mu;
    mm[tid] = mu; rr[tid] = rsqrtf(var + 1e-5f);
  }
  __syncthreads();
  for (int i = tid; i < 64 * 192; i += 256) {
    int pp = i / 192, c = i - pp * 192;
    float v = (tile[pp][c] - mm[pp]) * rr[pp];
    fcat[(size_t)(P0 + pp) * 384 + zoff + c] = (f16)v;
  }
}

// ---------------- cnorm of pixel-major fp32 -> pixel-major f16 --------------
__global__ __launch_bounds__(256) void norm_pm_kernel(const float* __restrict__ xpm,
                                                      f16* __restrict__ outn) {
  __shared__ float tile[64][193];
  __shared__ float rsum[64][4], rsq[64][4], mm[64], rr[64];
  int tid = threadIdx.x;
  int P0 = blockIdx.x * 64;
  for (int i = tid; i < 64 * 192; i += 256) {
    int pp = i / 192, c = i - pp * 192;
    tile[pp][c] = xpm[(size_t)(P0 + pp) * 192 + c];
  }
  __syncthreads();
  {
    int pp = tid >> 2, q = tid & 3;
    float s = 0.f, s2 = 0.f;
    for (int c = q * 48; c < q * 48 + 48; c++) { float v = tile[pp][c]; s += v; s2 += v * v; }
    rsum[pp][q] = s; rsq[pp][q] = s2;
  }
  __syncthreads();
  if (tid < 64) {
    float s  = rsum[tid][0] + rsum[tid][1] + rsum[tid][2] + rsum[tid][3];
    float s2 = rsq[tid][0] + rsq[tid][1] + rsq[tid][2] + rsq[tid][3];
    float mu = s * (1.f / 192.f);
    float var = s2 * (1.f / 192.f) - mu * mu;
    mm[tid] = mu; rr[tid] = rsqrtf(var + 1e-5f);
  }
  __syncthreads();
  for (int i = tid; i < 64 * 192; i += 256) {
    int pp = i / 192, c = i - pp * 192;
    outn[(size_t)(P0 + pp) * 192 + c] = (f16)((tile[pp][c] - mm[pp]) * rr[pp]);
  }
}

// ---------------- generic 128x128x32 MFMA GEMM with epilogue modes ----------
// MODE 0: plain f16 store        (qkv, pin)
// MODE 1: gelu + w_g2 row-reduction into alpha_acc atomics (g1 gemm, no store)
// MODE 2: A = [alpha*v_raw ; (1-alpha)*v_rgb]; epi: +b_fc +Frn +Fyn -> fp32 outpm
// MODE 3: epi: + outpm residual, LDS-transpose, store NCHW fp32 d_out (pout)
struct GArgs {
  const f16* A; long lda; long aoff;
  const f16* B1; const f16* B2; int b1rows; int Nout; int K; long bStride;
  f16* outH; long ldo;
  const float* bfc; const f16* fcat; float* outpm;
  const float* bg1; const float* wg2; float* alpha_acc;
  const f16* vraw; const f16* vrgb; const float* alpha_pre; const float* bg2;
  const float* outpm_r; float* dout;
};

template <int MODE>
__global__ __launch_bounds__(256) void gemm_k(GArgs g) {
  __shared__ __align__(16) char smem[21504];
  f16 (*As)[40] = (f16(*)[40])smem;            // 128 x (32+8) f16 = 10240 B
  f16 (*Bs)[40] = (f16(*)[40])(smem + 10240);  // 10240 B
  float* salpha = (float*)(smem + 20480);      // 512 B (MODE 2)

  int tid = threadIdx.x;
  int P0 = blockIdx.y * 128;
  int n0 = blockIdx.x * 128;
  int wave = tid >> 6, lane = tid & 63, l15 = lane & 15, quad = lane >> 4;
  int m_off = (wave >> 1) * 64, n_off = (wave & 1) * 64;
  const f16* B1 = g.B1 + (size_t)(P0 >> 14) * g.bStride;

  if (MODE == 2) {
    if (tid < 128) {
      float a = g.alpha_pre[P0 + tid] + g.bg2[0];
      salpha[tid] = 1.f / (1.f + __expf(-a));
    }
  }
  __syncthreads();

  float4v acc[4][4];
#pragma unroll
  for (int i = 0; i < 4; i++)
#pragma unroll
    for (int j = 0; j < 4; j++) acc[i][j] = (float4v){0.f, 0.f, 0.f, 0.f};

  int srow = tid >> 2;
  int scc  = (tid & 3) * 8;

  for (int k0 = 0; k0 < g.K; k0 += 32) {
    uint4 av[2], bv[2];
#pragma unroll
    for (int h = 0; h < 2; h++) {
      int row = srow + h * 64;
      if (MODE == 2) {
        int k = k0 + scc;
        const f16* src = (k < 192) ? (g.vraw + (size_t)(P0 + row) * 576 + 192 + k)
                                   : (g.vrgb + (size_t)(P0 + row) * 576 + k);
        float s = (k < 192) ? salpha[row] : (1.f - salpha[row]);
        U4H8 t; t.u = *(const uint4*)src;
#pragma unroll
        for (int e = 0; e < 8; e++) t.h[e] = (f16)((float)t.h[e] * s);
        av[h] = t.u;
      } else {
        av[h] = *(const uint4*)(g.A + (size_t)(P0 + row) * g.lda + g.aoff + k0 + scc);
      }
      int n = n0 + row;
      uint4 bb = {0u, 0u, 0u, 0u};
      if (n < g.b1rows)      bb = *(const uint4*)(B1 + (size_t)n * g.K + k0 + scc);
      else if (n < g.Nout)   bb = *(const uint4*)(g.B2 + (size_t)(n - g.b1rows) * g.K + k0 + scc);
      bv[h] = bb;
    }
    __syncthreads();   // previous tile consumed
#pragma unroll
    for (int h = 0; h < 2; h++) {
      *(uint4*)&As[srow + h * 64][scc] = av[h];
      *(uint4*)&Bs[srow + h * 64][scc] = bv[h];
    }
    __syncthreads();
    half8 af[4], bf[4];
#pragma unroll
    for (int i = 0; i < 4; i++) af[i] = *(const half8*)&As[m_off + i * 16 + l15][quad * 8];
#pragma unroll
    for (int i = 0; i < 4; i++) bf[i] = *(const half8*)&Bs[n_off + i * 16 + l15][quad * 8];
#pragma unroll
    for (int mi = 0; mi < 4; mi++)
#pragma unroll
      for (int ni = 0; ni < 4; ni++)
        acc[mi][ni] = __builtin_amdgcn_mfma_f32_16x16x32_f16(af[mi], bf[ni], acc[mi][ni], 0, 0, 0);
  }

  if (MODE == 0) {
#pragma unroll
    for (int mi = 0; mi < 4; mi++) {
      int row = P0 + m_off + mi * 16 + quad * 4;
#pragma unroll
      for (int ni = 0; ni < 4; ni++) {
        int gcol = n0 + n_off + ni * 16 + l15;
        if (gcol < g.Nout) {
#pragma unroll
          for (int r = 0; r < 4; r++)
            g.outH[(size_t)(row + r) * g.ldo + gcol] = (f16)acc[mi][ni][r];
        }
      }
    }
  } else if (MODE == 1) {
    float bg[4], wg[4];
#pragma unroll
    for (int ni = 0; ni < 4; ni++) {
      int gcol = n0 + n_off + ni * 16 + l15;
      bg[ni] = g.bg1[gcol]; wg[ni] = g.wg2[gcol];
    }
    float psum[4][4];
#pragma unroll
    for (int mi = 0; mi < 4; mi++)
#pragma unroll
      for (int r = 0; r < 4; r++) psum[mi][r] = 0.f;
#pragma unroll
    for (int mi = 0; mi < 4; mi++)
#pragma unroll
      for (int ni = 0; ni < 4; ni++)
#pragma unroll
        for (int r = 0; r < 4; r++) {
          float xx = acc[mi][ni][r] + bg[ni];
          float ge = 0.5f * xx * (1.f + erff(xx * 0.70710678118f));
          psum[mi][r] += ge * wg[ni];
        }
#pragma unroll
    for (int s = 1; s < 16; s <<= 1)
#pragma unroll
      for (int mi = 0; mi < 4; mi++)
#pragma unroll
        for (int r = 0; r < 4; r++) psum[mi][r] += __shfl_xor(psum[mi][r], s, 64);
    if (l15 == 0) {
#pragma unroll
      for (int mi = 0; mi < 4; mi++)
#pragma unroll
        for (int r = 0; r < 4; r++)
          atomicAdd(&g.alpha_acc[P0 + m_off + mi * 16 + quad * 4 + r], psum[mi][r]);
    }
  } else if (MODE == 2) {
#pragma unroll
    for (int mi = 0; mi < 4; mi++) {
      int prow = P0 + m_off + mi * 16 + quad * 4;
#pragma unroll
      for (int ni = 0; ni < 4; ni++) {
        int gcol = n0 + n_off + ni * 16 + l15;
        if (gcol < 192) {
#pragma unroll
          for (int r = 0; r < 4; r++) {
            size_t P = (size_t)(prow + r);
            float v = acc[mi][ni][r] + g.bfc[gcol] +
                      (float)g.fcat[P * 384 + gcol] + (float)g.fcat[P * 384 + 192 + gcol];
            g.outpm[P * 192 + gcol] = v;
          }
        }
      }
    }
  } else {  // MODE 3
#pragma unroll
    for (int mi = 0; mi < 4; mi++) {
      int prow = P0 + m_off + mi * 16 + quad * 4;
#pragma unroll
      for (int ni = 0; ni < 4; ni++) {
        int gcol = n0 + n_off + ni * 16 + l15;
        if (gcol < 192) {
#pragma unroll
          for (int r = 0; r < 4; r++)
            acc[mi][ni][r] += g.outpm_r[(size_t)(prow + r) * 192 + gcol];
        }
      }
    }
    float (*bounce)[129] = (float(*)[129])smem;  // 32 x 129 fp32 = 16512 B
    for (int cg = 0; cg < 4; cg++) {
      __syncthreads();
      if ((wave & 1) == (cg >> 1)) {
#pragma unroll
        for (int nn = 0; nn < 2; nn++) {
          int ni = (cg & 1) * 2 + nn;
          int lc = nn * 16 + l15;
#pragma unroll
          for (int mi = 0; mi < 4; mi++)
#pragma unroll
            for (int r = 0; r < 4; r++)
              bounce[lc][m_off + mi * 16 + quad * 4 + r] = acc[mi][ni][r];
        }
      }
      __syncthreads();
      int c = tid >> 3, ps = (tid & 7) * 16;
      int gc = n0 + cg * 32 + c;
      if (gc < 192) {
        int b = P0 >> 14, p = (P0 & (HW - 1)) + ps;
        float* dst = g.dout + ((size_t)b * 192 + gc) * HW + p;
#pragma unroll
        for (int i = 0; i < 16; i++) dst[i] = bounce[c][ps + i];
      }
    }
  }
}

// ---------------- qkv pixel-major -> channel-major transpose (q,k only) -----
// out qkT[(t*2+b)][row 0..383][16384]: row<192 = k-ch row, row>=192 = q-ch (row-192)
__global__ __launch_bounds__(256) void qk_transpose_kernel(const f16* __restrict__ qkvR,
                                                           const f16* __restrict__ qkvG,
                                                           f16* __restrict__ qkT) {
  __shared__ f16 T[64][264];     // row stride 264 f16 = 528 B (16B-mult, 132 dw)
  int tid = threadIdx.x;
  int p0 = blockIdx.x * 256;
  int g  = blockIdx.y;           // channel group 0..5
  int t  = blockIdx.z >> 1, b = blockIdx.z & 1;
  const f16* src = t ? qkvG : qkvR;
  int col0 = (g < 3) ? g * 64 : g * 64 + 192;   // k cols 0..191, q cols 384..575
#pragma unroll
  for (int i = 0; i < 4; i++) {
    int idx = i * 256 + tid;
    int pp = idx >> 3, c8 = (idx & 7) * 8;      // pixel pair, channel octet
    const f16* s0 = src + ((size_t)(b * HW + p0 + 2 * pp)) * 576 + col0 + c8;
    uint4 v0 = *(const uint4*)s0;
    uint4 v1 = *(const uint4*)(s0 + 576);
    const unsigned* a = (const unsigned*)&v0;
    const unsigned* c = (const unsigned*)&v1;
#pragma unroll
    for (int w = 0; w < 4; w++) {
      unsigned lo = (a[w] & 0xffffu) | (c[w] << 16);
      unsigned hi = (a[w] >> 16) | (c[w] & 0xffff0000u);
      *(unsigned*)&T[c8 + 2 * w][2 * pp]     = lo;
      *(unsigned*)&T[c8 + 2 * w + 1][2 * pp] = hi;
    }
  }
  __syncthreads();
  size_t obase = ((size_t)(t * 2 + b) * 384 + g * 64) * 16384 + p0;
#pragma unroll
  for (int i = 0; i < 8; i++) {
    int idx = i * 256 + tid;
    int row = idx >> 5, p8 = (idx & 31) * 8;
    *(uint4*)(qkT + obase + (size_t)row * 16384 + p8) = *(const uint4*)&T[row][p8];
  }
}

// ---------------- split-K MFMA Gram + sum-of-squares ------------------------
// grid (16 kchunks, h*2+pair, b). Per block: A=[48 x 1024] q-chs, B=[48 x 1024] k-chs
// gram layout per (b,h): [G_pair0 2304 | G_pair1 2304 | nsq 4*48]  (fp32, atomic)
__global__ __launch_bounds__(256) void gram_mfma_kernel(const f16* __restrict__ qkT,
                                                        float* __restrict__ gram) {
  __shared__ __align__(16) f16 As[48][136];
  __shared__ __align__(16) f16 Bs[48][136];
  __shared__ float Gacc[48][49];
  int tid = threadIdx.x;
  int chunk = blockIdx.x;
  int h = blockIdx.y >> 1, pair = blockIdx.y & 1;
  int b = blockIdx.z;
  int tA = pair ? 0 : 1, tB = pair ? 1 : 0;   // pair0: q_rgb . k_raw ; pair1: q_raw . k_rgb
  const f16* Abase = qkT + ((size_t)(tA * 2 + b) * 384 + 192 + 48 * h) * 16384;
  const f16* Bbase = qkT + ((size_t)(tB * 2 + b) * 384 + 48 * h) * 16384;
  for (int i = tid; i < 48 * 49; i += 256) ((float*)Gacc)[i] = 0.f;
  int wave = tid >> 6, lane = tid & 63, l15 = lane & 15, quad = lane >> 4;
  float4v acc[3][3];
#pragma unroll
  for (int i = 0; i < 3; i++)
#pragma unroll
    for (int j = 0; j < 3; j++) acc[i][j] = (float4v){0.f, 0.f, 0.f, 0.f};
  float ns_acc = 0.f;
  int nrow = tid >> 1, nhalf = tid & 1;

  for (int stage = 0; stage < 8; stage++) {
    int k0 = chunk * 1024 + stage * 128;
    uint4 v[6];
#pragma unroll
    for (int i = 0; i < 6; i++) {
      int idx = i * 256 + tid;
      int row = idx >> 4, seg = (idx & 15) * 8;
      const f16* p = (row < 48) ? (Abase + (size_t)row * 16384 + k0 + seg)
                                : (Bbase + (size_t)(row - 48) * 16384 + k0 + seg);
      v[i] = *(const uint4*)p;
    }
    __syncthreads();   // previous tile fully consumed
#pragma unroll
    for (int i = 0; i < 6; i++) {
      int idx = i * 256 + tid;
      int row = idx >> 4, seg = (idx & 15) * 8;
      f16* dst = (row < 48) ? &As[row][seg] : &Bs[row - 48][seg];
      *(uint4*)dst = v[i];
    }
    __syncthreads();
    int kk = wave * 32;
    half8 af[3], bf[3];
#pragma unroll
    for (int i = 0; i < 3; i++) {
      af[i] = *(const half8*)&As[i * 16 + l15][kk + quad * 8];
      bf[i] = *(const half8*)&Bs[i * 16 + l15][kk + quad * 8];
    }
#pragma unroll
    for (int mi = 0; mi < 3; mi++)
#pragma unroll
      for (int ni = 0; ni < 3; ni++)
        acc[mi][ni] = __builtin_amdgcn_mfma_f32_16x16x32_f16(af[mi], bf[ni], acc[mi][ni], 0, 0, 0);
    if (tid < 192) {
      const f16* r = (nrow < 48) ? &As[nrow][nhalf * 64] : &Bs[nrow - 48][nhalf * 64];
#pragma unroll
      for (int e = 0; e < 8; e++) {
        U4H8 tt; tt.u = *(const uint4*)(r + e * 8);
#pragma unroll
        for (int j = 0; j < 8; j++) { float x = (float)tt.h[j]; ns_acc += x * x; }
      }
    }
  }
  __syncthreads();
  for (int w = 0; w < 4; w++) {
    if (wave == w) {
#pragma unroll
      for (int mi = 0; mi < 3; mi++)
#pragma unroll
        for (int ni = 0; ni < 3; ni++)
#pragma unroll
          for (int r = 0; r < 4; r++)
            Gacc[mi * 16 + quad * 4 + r][ni * 16 + l15] += acc[mi][ni][r];
    }
    __syncthreads();
  }
  float* base = gram + ((size_t)b * 4 + h) * 4800;
  float* G = base + pair * 2304;
  for (int i = tid; i < 2304; i += 256)
    atomicAdd(G + i, Gacc[i / 48][i - (i / 48) * 48]);
  if (tid < 192) {
    int slot = pair * 2 + (nrow >= 48 ? 1 : 0);
    int ch = (nrow >= 48) ? (nrow - 48) : nrow;
    atomicAdd(base + 4608 + slot * 48 + ch, ns_acc);
  }
}

// ---------------- softmax over 48 cols of 16 tiny matrices ------------------
__global__ void softmax_kernel(const float* __restrict__ gram, const float* __restrict__ temp,
                               float* __restrict__ att) {
  int id = blockIdx.x;                    // 16 = b*8 + h*2 + pr
  int b = id >> 3, h = (id >> 1) & 3, pr = id & 1;
  int tid = threadIdx.x;                  // 64
  __shared__ float srk[48];
  const float* base = gram + ((size_t)b * 4 + h) * 4800;
  const float* G  = base + pr * 2304;
  const float* nq = base + 4608 + (pr ? 96 : 0);
  const float* nk = base + 4608 + (pr ? 144 : 48);
  if (tid < 48) srk[tid] = 1.f / fmaxf(sqrtf(nk[tid]), 1e-12f);
  __syncthreads();
  if (tid < 48) {
    float rq = 1.f / fmaxf(sqrtf(nq[tid]), 1e-12f);
    float T = temp[h];
    float s[48], mx = -1e30f;
#pragma unroll
    for (int d = 0; d < 48; d++) { s[d] = T * G[tid * 48 + d] * rq * srk[d]; mx = fmaxf(mx, s[d]); }
    float sum = 0.f;
#pragma unroll
    for (int d = 0; d < 48; d++) { s[d] = __expf(s[d] - mx); sum += s[d]; }
    float inv = 1.f / sum;
    float* A = att + (((size_t)b * 2 + pr) * 4 + h) * 2304 + tid * 48;
#pragma unroll
    for (int d = 0; d < 48; d++) A[d] = s[d] * inv;
  }
}

// ---------------- M_cat = [W_fc*blkdiag(A_raw) | W_fc*blkdiag(A_rgb)] -------
__global__ __launch_bounds__(256) void mbuild_kernel(const float* __restrict__ wfc,
                                                     const float* __restrict__ att,
                                                     f16* __restrict__ mcat) {
  int e = blockIdx.x * 256 + threadIdx.x;
  if (e >= 147456) return;
  int b = e / 73728, r = e - b * 73728;
  int o = r / 384, j = r - o * 384;
  int pr = j / 192, jj = j - pr * 192;
  int h = jj / 48, d = jj - h * 48;
  const float* A = att + (((size_t)b * 2 + pr) * 4 + h) * 2304 + d;
  const float* w = wfc + o * 192 + h * 48;
  float s = 0.f;
  for (int c = 0; c < 48; c++) s += w[c] * A[c * 48];
  mcat[(size_t)b * 73728 + o * 384 + j] = (f16)s;
}

// ---------------- fused pshuffle -> dwconv5x5 & dil-3x3 -> mish -> punshuffle
__global__ __launch_bounds__(256) void dwmish_kernel(const f16* __restrict__ hid,
                                                     const float* __restrict__ w5,
                                                     const float* __restrict__ w3,
                                                     f16* __restrict__ u) {
  __shared__ f16 sx[324][8];   // 18x18 pixels x (4 x1-subch + 4 x2-subch)
  __shared__ float sw5[25], sw3[9];
  int tid = threadIdx.x;
  int c = blockIdx.y, b = blockIdx.z;
  int ti0 = (blockIdx.x >> 3) * 16, tj0 = (blockIdx.x & 7) * 16;
  if (tid < 25) sw5[tid] = w5[c * 25 + tid];
  if (tid >= 32 && tid < 41) sw3[tid - 32] = w3[c * 9 + tid - 32];
  for (int ii = tid; ii < 648; ii += 256) {
    int pix = ii >> 1, half = ii & 1;
    int pi = pix / 18, pj = pix - pi * 18;
    int gi = ti0 - 1 + pi, gj = tj0 - 1 + pj;
    uint2 v = {0u, 0u};
    if (gi >= 0 && gi < 128 && gj >= 0 && gj < 128)
      v = *(const uint2*)(hid + ((size_t)b * HW + gi * 128 + gj) * 1024 + half * 512 + c * 4);
    *(uint2*)&sx[pix][half * 4] = v;
  }
  __syncthreads();
  int ti = tid >> 4, tj = tid & 15;
  int gi = ti0 + ti, gj = tj0 + tj;
  U2H4 res;
#pragma unroll
  for (int pq = 0; pq < 4; pq++) {
    int p = pq >> 1, q = pq & 1;
    float a2 = 0.f;
#pragma unroll
    for (int ky = 0; ky < 3; ky++)
#pragma unroll
      for (int kx = 0; kx < 3; kx++)
        a2 += sw3[ky * 3 + kx] * (float)sx[(ti + ky) * 18 + tj + kx][4 + pq];
    float a1 = 0.f;
#pragma unroll
    for (int dy = -2; dy <= 2; dy++)
#pragma unroll
      for (int dx = -2; dx <= 2; dx++) {
        int s = p + dy, t2 = q + dx;
        int di = s >> 1, ps_ = s & 1;
        int dj = t2 >> 1, qs_ = t2 & 1;
        a1 += sw5[(dy + 2) * 5 + dx + 2] * (float)sx[(ti + 1 + di) * 18 + tj + 1 + dj][ps_ * 2 + qs_];
      }
    float sp = (a2 > 15.f) ? a2 : log1pf(__expf(a2));
    res.h[pq] = (f16)(a2 * tanhf(sp) * a1);
  }
  *(uint2*)(u + ((size_t)b * HW + gi * 128 + gj) * 512 + c * 4) = res.u;
}

// ---------------------------------------------------------------------------
extern "C" void kernel_launch(void* const* d_in, const int* in_sizes, int n_in,
                              void* d_out, int out_size, void* d_ws, size_t ws_size,
                              hipStream_t stream) {
  const float* F_raw    = (const float*)d_in[0];
  const float* F_Y      = (const float*)d_in[1];
  const float* temp     = (const float*)d_in[2];
  const float* w_raw_kv = (const float*)d_in[3];
  const float* w_raw_q  = (const float*)d_in[4];
  const float* w_rgb_kv = (const float*)d_in[5];
  const float* w_rgb_q  = (const float*)d_in[6];
  const float* w_g1     = (const float*)d_in[7];
  const float* b_g1     = (const float*)d_in[8];
  const float* w_g2     = (const float*)d_in[9];
  const float* b_g2     = (const float*)d_in[10];
  const float* w_fc     = (const float*)d_in[11];
  const float* b_fc     = (const float*)d_in[12];
  const float* w_pin    = (const float*)d_in[13];
  const float* w_dw5    = (const float*)d_in[14];
  const float* w_dwd    = (const float*)d_in[15];
  const float* w_pout   = (const float*)d_in[16];
  char* ws = (char*)d_ws;
  float* dout = (float*)d_out;

  const size_t O_FCAT  = 0;            // 25,165,824  f16 Fcat (NPIX x 384)
  const size_t O_QKV0  = 25165824;     // 37,748,736  f16 raw [k|v|q] (NPIX x 576)
  const size_t O_QKV1  = 62914560;     // 37,748,736  f16 rgb
  const size_t O_ALPHA = 100663296;    // 131,072     fp32 alpha pre-sigmoid
  const size_t O_GRAM  = 100794368;    // 153,600     fp32 grams+normsq
  const size_t O_ATT   = 100947968;    // 147,456     fp32 softmaxed attn
  const size_t O_MCAT  = 101095424;    // 294,912     f16 M_cat (2 x 192 x 384)
  const size_t O_WB    = 101390336;    // 1,622,016   f16 converted weights
  const size_t O_OUTPM = 103012352;    // 25,165,824  fp32 out pixel-major
  const size_t O_QKT   = 103012352;    // 50,331,648  f16 qkT (dead before ctx gemm)
  const size_t O_NORM  = 128178176;    // 12,582,912  f16 cnorm(out)
  const size_t O_HID   = O_QKV0;       // 67,108,864  f16 hidden (reuses dead qkv)
  const size_t O_U     = 140761088;    // 33,554,432  f16 u  (ends 174,315,520)
  if (ws_size < 174315520) return;

  f16* wb      = (f16*)(ws + O_WB);
  f16* wb_kvR  = wb;
  f16* wb_qR   = wb + 73728;
  f16* wb_kvG  = wb + 110592;
  f16* wb_qG   = wb + 184320;
  f16* wb_g1   = wb + 221184;
  f16* wb_pin  = wb + 516096;
  f16* wb_pout = wb + 712704;

  WConvArgs wa;
  wa.src[0] = w_raw_kv; wa.dst[0] = wb_kvR;  wa.n[0] = 73728;
  wa.src[1] = w_raw_q;  wa.dst[1] = wb_qR;   wa.n[1] = 36864;
  wa.src[2] = w_rgb_kv; wa.dst[2] = wb_kvG;  wa.n[2] = 73728;
  wa.src[3] = w_rgb_q;  wa.dst[3] = wb_qG;   wa.n[3] = 36864;
  wa.src[4] = w_g1;     wa.dst[4] = wb_g1;   wa.n[4] = 294912;
  wa.src[5] = w_pin;    wa.dst[5] = wb_pin;  wa.n[5] = 196608;
  wa.src[6] = w_pout;   wa.dst[6] = wb_pout; wa.n[6] = 98304;
  wconv_kernel<<<dim3(16, 7), 256, 0, stream>>>(wa);

  hipMemsetAsync(ws + O_ALPHA, 0, 131072 + 153600, stream);

  f16* fcat = (f16*)(ws + O_FCAT);
  cnorm_in_kernel<<<512, 256, 0, stream>>>(F_raw, fcat, 0);
  cnorm_in_kernel<<<512, 256, 0, stream>>>(F_Y, fcat, 192);

  {  // qkv raw + rgb
    GArgs a = {};
    a.A = fcat; a.lda = 384; a.aoff = 0;
    a.B1 = wb_kvR; a.B2 = wb_qR; a.b1rows = 384; a.Nout = 576; a.K = 192; a.bStride = 0;
    a.outH = (f16*)(ws + O_QKV0); a.ldo = 576;
    gemm_k<0><<<dim3(5, 256), 256, 0, stream>>>(a);
    a.aoff = 192; a.B1 = wb_kvG; a.B2 = wb_qG; a.outH = (f16*)(ws + O_QKV1);
    gemm_k<0><<<dim3(5, 256), 256, 0, stream>>>(a);
  }
  {  // g1 gemm with gelu + alpha row-reduction
    GArgs a = {};
    a.A = fcat; a.lda = 384; a.aoff = 0;
    a.B1 = wb_g1; a.B2 = wb_g1; a.b1rows = 768; a.Nout = 768; a.K = 384; a.bStride = 0;
    a.bg1 = b_g1; a.wg2 = w_g2; a.alpha_acc = (float*)(ws + O_ALPHA);
    gemm_k<1><<<dim3(6, 256), 256, 0, stream>>>(a);
  }
  qk_transpose_kernel<<<dim3(64, 6, 4), 256, 0, stream>>>((const f16*)(ws + O_QKV0),
                                                          (const f16*)(ws + O_QKV1),
                                                          (f16*)(ws + O_QKT));
  gram_mfma_kernel<<<dim3(16, 8, 2), 256, 0, stream>>>((const f16*)(ws + O_QKT),
                                                       (float*)(ws + O_GRAM));
  softmax_kernel<<<16, 64, 0, stream>>>((const float*)(ws + O_GRAM), temp, (float*)(ws + O_ATT));
  mbuild_kernel<<<576, 256, 0, stream>>>(w_fc, (const float*)(ws + O_ATT), (f16*)(ws + O_MCAT));
  {  // ctx + fc + residual -> outpm fp32
    GArgs a = {};
    a.B1 = (const f16*)(ws + O_MCAT); a.B2 = (const f16*)(ws + O_MCAT);
    a.b1rows = 192; a.Nout = 192; a.K = 384; a.bStride = 73728;
    a.vraw = (const f16*)(ws + O_QKV0); a.vrgb = (const f16*)(ws + O_QKV1);
    a.alpha_pre = (float*)(ws + O_ALPHA); a.bg2 = b_g2;
    a.bfc = b_fc; a.fcat = fcat; a.outpm = (float*)(ws + O_OUTPM);
    gemm_k<2><<<dim3(2, 256), 256, 0, stream>>>(a);
  }
  norm_pm_kernel<<<512, 256, 0, stream>>>((const float*)(ws + O_OUTPM), (f16*)(ws + O_NORM));
  {  // pin gemm -> hidden
    GArgs a = {};
    a.A = (const f16*)(ws + O_NORM); a.lda = 192; a.aoff = 0;
    a.B1 = wb_pin; a.B2 = wb_pin; a.b1rows = 1024; a.Nout = 1024; a.K = 192; a.bStride = 0;
    a.outH = (f16*)(ws + O_HID); a.ldo = 1024;
    gemm_k<0><<<dim3(8, 256), 256, 0, stream>>>(a);
  }
  dwmish_kernel<<<dim3(64, 128, 2), 256, 0, stream>>>((const f16*)(ws + O_HID), w_dw5, w_dwd,
                                                      (f16*)(ws + O_U));
  {  // pout gemm + residual -> d_out (NCHW fp32)
    GArgs a = {};
    a.A = (const f16*)(ws + O_U); a.lda = 512; a.aoff = 0;
    a.B1 = wb_pout; a.B2 = wb_pout; a.b1rows = 192; a.Nout = 192; a.K = 512; a.bStride = 0;
    a.outpm_r = (const float*)(ws + O_OUTPM); a.dout = dout;
    gemm_k<3><<<dim3(2, 256), 256, 0, stream>>>(a);
  }
}

// Round 3
// 634.863 us; speedup vs baseline: 1.5167x; 1.1838x over previous
//
#include <hip/hip_runtime.h>
#include <cstdint>
#include <cstddef>

// ---------------------------------------------------------------------------
// DynamicReflectionAttention fused pipeline for MI355X (gfx950)
// Layouts: all intermediate activations are PIXEL-MAJOR fp16:
//   X[(b*HW + p)][channel], row stride = channel count.
// GEMMs: C[pixel][outch] = sum_k X[pixel][k] * W[outch][k]  (MFMA 16x16x32 f16)
// ---------------------------------------------------------------------------

typedef _Float16 f16;
using half8  = __attribute__((ext_vector_type(8))) _Float16;
using float4v = __attribute__((ext_vector_type(4))) float;

#define HW    16384
#define NPIX  32768

union U4H8 { uint4 u; f16 h[8]; };
union U2H4 { uint2 u; f16 h[4]; };

// ---------------- weight fp32 -> fp16 convert (7 tensors, one launch) -------
struct WConvArgs { const float* src[7]; f16* dst[7]; int n[7]; };
__global__ __launch_bounds__(256) void wconv_kernel(WConvArgs a) {
  int t = blockIdx.y;
  const float* s = a.src[t]; f16* d = a.dst[t]; int n = a.n[t];
  for (int i = blockIdx.x * 256 + threadIdx.x; i < n; i += gridDim.x * 256)
    d[i] = (f16)s[i];
}

// ---------------- cnorm of NCHW fp32 input -> pixel-major f16 Fcat ----------
__global__ __launch_bounds__(256) void cnorm_in_kernel(const float* __restrict__ x,
                                                       f16* __restrict__ fcat, int zoff) {
  __shared__ float tile[64][193];
  __shared__ float rsum[64][4], rsq[64][4], mm[64], rr[64];
  int tid = threadIdx.x;
  int P0 = blockIdx.x * 64;
  int b  = P0 >> 14;
  int p0 = P0 & (HW - 1);
  for (int i = tid; i < 64 * 192; i += 256) {
    int c = i >> 6, pp = i & 63;
    tile[pp][c] = x[((size_t)(b * 192 + c)) * HW + p0 + pp];
  }
  __syncthreads();
  {
    int pp = tid >> 2, q = tid & 3;
    float s = 0.f, s2 = 0.f;
    for (int c = q * 48; c < q * 48 + 48; c++) { float v = tile[pp][c]; s += v; s2 += v * v; }
    rsum[pp][q] = s; rsq[pp][q] = s2;
  }
  __syncthreads();
  if (tid < 64) {
    float s  = rsum[tid][0] + rsum[tid][1] + rsum[tid][2] + rsum[tid][3];
    float s2 = rsq[tid][0] + rsq[tid][1] + rsq[tid][2] + rsq[tid][3];
    float mu = s * (1.f / 192.f);
    float var = s2 * (1.f / 192.f) - mu * mu;
    mm[tid] = mu; rr[tid] = rsqrtf(var + 1e-5f);
  }
  __syncthreads();
  for (int i = tid; i < 64 * 192; i += 256) {
    int pp = i / 192, c = i - pp * 192;
    float v = (tile[pp][c] - mm[pp]) * rr[pp];
    fcat[(size_t)(P0 + pp) * 384 + zoff + c] = (f16)v;
  }
}

// ---------------- cnorm of pixel-major fp32 -> pixel-major f16 --------------
__global__ __launch_bounds__(256) void norm_pm_kernel(const float* __restrict__ xpm,
                                                      f16* __restrict__ outn) {
  __shared__ float tile[64][193];
  __shared__ float rsum[64][4], rsq[64][4], mm[64], rr[64];
  int tid = threadIdx.x;
  int P0 = blockIdx.x * 64;
  for (int i = tid; i < 64 * 192; i += 256) {
    int pp = i / 192, c = i - pp * 192;
    tile[pp][c] = xpm[(size_t)(P0 + pp) * 192 + c];
  }
  __syncthreads();
  {
    int pp = tid >> 2, q = tid & 3;
    float s = 0.f, s2 = 0.f;
    for (int c = q * 48; c < q * 48 + 48; c++) { float v = tile[pp][c]; s += v; s2 += v * v; }
    rsum[pp][q] = s; rsq[pp][q] = s2;
  }
  __syncthreads();
  if (tid < 64) {
    float s  = rsum[tid][0] + rsum[tid][1] + rsum[tid][2] + rsum[tid][3];
    float s2 = rsq[tid][0] + rsq[tid][1] + rsq[tid][2] + rsq[tid][3];
    float mu = s * (1.f / 192.f);
    float var = s2 * (1.f / 192.f) - mu * mu;
    mm[tid] = mu; rr[tid] = rsqrtf(var + 1e-5f);
  }
  __syncthreads();
  for (int i = tid; i < 64 * 192; i += 256) {
    int pp = i / 192, c = i - pp * 192;
    outn[(size_t)(P0 + pp) * 192 + c] = (f16)((tile[pp][c] - mm[pp]) * rr[pp]);
  }
}

// ---------------- generic 128x128x32 MFMA GEMM with epilogue modes ----------
// MODE 0: plain f16 store        (qkv, pin)
// MODE 1: gelu + w_g2 row-reduction into alpha_acc atomics (g1 gemm, no store)
// MODE 2: A = [alpha*v_raw ; (1-alpha)*v_rgb]; epi: +b_fc +Frn +Fyn -> fp32 outpm
// MODE 3: epi: + outpm residual, LDS-transpose, store NCHW fp32 d_out (pout)
struct GArgs {
  const f16* A; long lda; long aoff;
  const f16* B1; const f16* B2; int b1rows; int Nout; int K; long bStride;
  f16* outH; long ldo;
  const float* bfc; const f16* fcat; float* outpm;
  const float* bg1; const float* wg2; float* alpha_acc;
  const f16* vraw; const f16* vrgb; const float* alpha_pre; const float* bg2;
  const float* outpm_r; float* dout;
};

template <int MODE>
__global__ __launch_bounds__(256) void gemm_k(GArgs g) {
  __shared__ __align__(16) char smem[21504];
  f16 (*As)[40] = (f16(*)[40])smem;            // 128 x (32+8) f16 = 10240 B
  f16 (*Bs)[40] = (f16(*)[40])(smem + 10240);  // 10240 B
  float* salpha = (float*)(smem + 20480);      // 512 B (MODE 2)

  int tid = threadIdx.x;
  int P0 = blockIdx.y * 128;
  int n0 = blockIdx.x * 128;
  int wave = tid >> 6, lane = tid & 63, l15 = lane & 15, quad = lane >> 4;
  int m_off = (wave >> 1) * 64, n_off = (wave & 1) * 64;
  const f16* B1 = g.B1 + (size_t)(P0 >> 14) * g.bStride;

  if (MODE == 2) {
    if (tid < 128) {
      float a = g.alpha_pre[P0 + tid] + g.bg2[0];
      salpha[tid] = 1.f / (1.f + __expf(-a));
    }
  }
  __syncthreads();

  float4v acc[4][4];
#pragma unroll
  for (int i = 0; i < 4; i++)
#pragma unroll
    for (int j = 0; j < 4; j++) acc[i][j] = (float4v){0.f, 0.f, 0.f, 0.f};

  int srow = tid >> 2;
  int scc  = (tid & 3) * 8;

  for (int k0 = 0; k0 < g.K; k0 += 32) {
    uint4 av[2], bv[2];
#pragma unroll
    for (int h = 0; h < 2; h++) {
      int row = srow + h * 64;
      if (MODE == 2) {
        int k = k0 + scc;
        const f16* src = (k < 192) ? (g.vraw + (size_t)(P0 + row) * 576 + 192 + k)
                                   : (g.vrgb + (size_t)(P0 + row) * 576 + k);
        float s = (k < 192) ? salpha[row] : (1.f - salpha[row]);
        U4H8 t; t.u = *(const uint4*)src;
#pragma unroll
        for (int e = 0; e < 8; e++) t.h[e] = (f16)((float)t.h[e] * s);
        av[h] = t.u;
      } else {
        av[h] = *(const uint4*)(g.A + (size_t)(P0 + row) * g.lda + g.aoff + k0 + scc);
      }
      int n = n0 + row;
      uint4 bb = {0u, 0u, 0u, 0u};
      if (n < g.b1rows)      bb = *(const uint4*)(B1 + (size_t)n * g.K + k0 + scc);
      else if (n < g.Nout)   bb = *(const uint4*)(g.B2 + (size_t)(n - g.b1rows) * g.K + k0 + scc);
      bv[h] = bb;
    }
    __syncthreads();   // previous tile consumed
#pragma unroll
    for (int h = 0; h < 2; h++) {
      *(uint4*)&As[srow + h * 64][scc] = av[h];
      *(uint4*)&Bs[srow + h * 64][scc] = bv[h];
    }
    __syncthreads();
    half8 af[4], bf[4];
#pragma unroll
    for (int i = 0; i < 4; i++) af[i] = *(const half8*)&As[m_off + i * 16 + l15][quad * 8];
#pragma unroll
    for (int i = 0; i < 4; i++) bf[i] = *(const half8*)&Bs[n_off + i * 16 + l15][quad * 8];
#pragma unroll
    for (int mi = 0; mi < 4; mi++)
#pragma unroll
      for (int ni = 0; ni < 4; ni++)
        acc[mi][ni] = __builtin_amdgcn_mfma_f32_16x16x32_f16(af[mi], bf[ni], acc[mi][ni], 0, 0, 0);
  }

  if (MODE == 0) {
#pragma unroll
    for (int mi = 0; mi < 4; mi++) {
      int row = P0 + m_off + mi * 16 + quad * 4;
#pragma unroll
      for (int ni = 0; ni < 4; ni++) {
        int gcol = n0 + n_off + ni * 16 + l15;
        if (gcol < g.Nout) {
#pragma unroll
          for (int r = 0; r < 4; r++)
            g.outH[(size_t)(row + r) * g.ldo + gcol] = (f16)acc[mi][ni][r];
        }
      }
    }
  } else if (MODE == 1) {
    float bg[4], wg[4];
#pragma unroll
    for (int ni = 0; ni < 4; ni++) {
      int gcol = n0 + n_off + ni * 16 + l15;
      bg[ni] = g.bg1[gcol]; wg[ni] = g.wg2[gcol];
    }
    float psum[4][4];
#pragma unroll
    for (int mi = 0; mi < 4; mi++)
#pragma unroll
      for (int r = 0; r < 4; r++) psum[mi][r] = 0.f;
#pragma unroll
    for (int mi = 0; mi < 4; mi++)
#pragma unroll
      for (int ni = 0; ni < 4; ni++)
#pragma unroll
        for (int r = 0; r < 4; r++) {
          float xx = acc[mi][ni][r] + bg[ni];
          float ge = 0.5f * xx * (1.f + erff(xx * 0.70710678118f));
          psum[mi][r] += ge * wg[ni];
        }
#pragma unroll
    for (int s = 1; s < 16; s <<= 1)
#pragma unroll
      for (int mi = 0; mi < 4; mi++)
#pragma unroll
        for (int r = 0; r < 4; r++) psum[mi][r] += __shfl_xor(psum[mi][r], s, 64);
    if (l15 == 0) {
#pragma unroll
      for (int mi = 0; mi < 4; mi++)
#pragma unroll
        for (int r = 0; r < 4; r++)
          atomicAdd(&g.alpha_acc[P0 + m_off + mi * 16 + quad * 4 + r], psum[mi][r]);
    }
  } else if (MODE == 2) {
#pragma unroll
    for (int mi = 0; mi < 4; mi++) {
      int prow = P0 + m_off + mi * 16 + quad * 4;
#pragma unroll
      for (int ni = 0; ni < 4; ni++) {
        int gcol = n0 + n_off + ni * 16 + l15;
        if (gcol < 192) {
#pragma unroll
          for (int r = 0; r < 4; r++) {
            size_t P = (size_t)(prow + r);
            float v = acc[mi][ni][r] + g.bfc[gcol] +
                      (float)g.fcat[P * 384 + gcol] + (float)g.fcat[P * 384 + 192 + gcol];
            g.outpm[P * 192 + gcol] = v;
          }
        }
      }
    }
  } else {  // MODE 3
#pragma unroll
    for (int mi = 0; mi < 4; mi++) {
      int prow = P0 + m_off + mi * 16 + quad * 4;
#pragma unroll
      for (int ni = 0; ni < 4; ni++) {
        int gcol = n0 + n_off + ni * 16 + l15;
        if (gcol < 192) {
#pragma unroll
          for (int r = 0; r < 4; r++)
            acc[mi][ni][r] += g.outpm_r[(size_t)(prow + r) * 192 + gcol];
        }
      }
    }
    float (*bounce)[129] = (float(*)[129])smem;  // 32 x 129 fp32 = 16512 B
    for (int cg = 0; cg < 4; cg++) {
      __syncthreads();
      if ((wave & 1) == (cg >> 1)) {
#pragma unroll
        for (int nn = 0; nn < 2; nn++) {
          int ni = (cg & 1) * 2 + nn;
          int lc = nn * 16 + l15;
#pragma unroll
          for (int mi = 0; mi < 4; mi++)
#pragma unroll
            for (int r = 0; r < 4; r++)
              bounce[lc][m_off + mi * 16 + quad * 4 + r] = acc[mi][ni][r];
        }
      }
      __syncthreads();
      int c = tid >> 3, ps = (tid & 7) * 16;
      int gc = n0 + cg * 32 + c;
      if (gc < 192) {
        int b = P0 >> 14, p = (P0 & (HW - 1)) + ps;
        float* dst = g.dout + ((size_t)b * 192 + gc) * HW + p;
#pragma unroll
        for (int i = 0; i < 16; i++) dst[i] = bounce[c][ps + i];
      }
    }
  }
}

// ---------------- qkv pixel-major -> channel-major transpose (q,k only) -----
// out qkT[(t*2+b)][row 0..383][16384]: row<192 = k-ch row, row>=192 = q-ch (row-192)
__global__ __launch_bounds__(256) void qk_transpose_kernel(const f16* __restrict__ qkvR,
                                                           const f16* __restrict__ qkvG,
                                                           f16* __restrict__ qkT) {
  __shared__ f16 T[64][264];     // row stride 264 f16 = 528 B (16B-mult, 132 dw)
  int tid = threadIdx.x;
  int p0 = blockIdx.x * 256;
  int g  = blockIdx.y;           // channel group 0..5
  int t  = blockIdx.z >> 1, b = blockIdx.z & 1;
  const f16* src = t ? qkvG : qkvR;
  int col0 = (g < 3) ? g * 64 : g * 64 + 192;   // k cols 0..191, q cols 384..575
#pragma unroll
  for (int i = 0; i < 4; i++) {
    int idx = i * 256 + tid;
    int pp = idx >> 3, c8 = (idx & 7) * 8;      // pixel pair, channel octet
    const f16* s0 = src + ((size_t)(b * HW + p0 + 2 * pp)) * 576 + col0 + c8;
    uint4 v0 = *(const uint4*)s0;
    uint4 v1 = *(const uint4*)(s0 + 576);
    const unsigned* a = (const unsigned*)&v0;
    const unsigned* c = (const unsigned*)&v1;
#pragma unroll
    for (int w = 0; w < 4; w++) {
      unsigned lo = (a[w] & 0xffffu) | (c[w] << 16);
      unsigned hi = (a[w] >> 16) | (c[w] & 0xffff0000u);
      *(unsigned*)&T[c8 + 2 * w][2 * pp]     = lo;
      *(unsigned*)&T[c8 + 2 * w + 1][2 * pp] = hi;
    }
  }
  __syncthreads();
  size_t obase = ((size_t)(t * 2 + b) * 384 + g * 64) * 16384 + p0;
#pragma unroll
  for (int i = 0; i < 8; i++) {
    int idx = i * 256 + tid;
    int row = idx >> 5, p8 = (idx & 31) * 8;
    *(uint4*)(qkT + obase + (size_t)row * 16384 + p8) = *(const uint4*)&T[row][p8];
  }
}

// ---------------- split-K MFMA Gram + sum-of-squares ------------------------
// grid (16 kchunks, h*2+pair, b). Per block: A=[48 x 1024] q-chs, B=[48 x 1024] k-chs
// gram layout per (b,h): [G_pair0 2304 | G_pair1 2304 | nsq 4*48]  (fp32, atomic)
__global__ __launch_bounds__(256) void gram_mfma_kernel(const f16* __restrict__ qkT,
                                                        float* __restrict__ gram) {
  __shared__ __align__(16) f16 As[48][136];
  __shared__ __align__(16) f16 Bs[48][136];
  __shared__ float Gacc[48][49];
  int tid = threadIdx.x;
  int chunk = blockIdx.x;
  int h = blockIdx.y >> 1, pair = blockIdx.y & 1;
  int b = blockIdx.z;
  int tA = pair ? 0 : 1, tB = pair ? 1 : 0;   // pair0: q_rgb . k_raw ; pair1: q_raw . k_rgb
  const f16* Abase = qkT + ((size_t)(tA * 2 + b) * 384 + 192 + 48 * h) * 16384;
  const f16* Bbase = qkT + ((size_t)(tB * 2 + b) * 384 + 48 * h) * 16384;
  for (int i = tid; i < 48 * 49; i += 256) ((float*)Gacc)[i] = 0.f;
  int wave = tid >> 6, lane = tid & 63, l15 = lane & 15, quad = lane >> 4;
  float4v acc[3][3];
#pragma unroll
  for (int i = 0; i < 3; i++)
#pragma unroll
    for (int j = 0; j < 3; j++) acc[i][j] = (float4v){0.f, 0.f, 0.f, 0.f};
  float ns_acc = 0.f;
  int nrow = tid >> 1, nhalf = tid & 1;

  for (int stage = 0; stage < 8; stage++) {
    int k0 = chunk * 1024 + stage * 128;
    uint4 v[6];
#pragma unroll
    for (int i = 0; i < 6; i++) {
      int idx = i * 256 + tid;
      int row = idx >> 4, seg = (idx & 15) * 8;
      const f16* p = (row < 48) ? (Abase + (size_t)row * 16384 + k0 + seg)
                                : (Bbase + (size_t)(row - 48) * 16384 + k0 + seg);
      v[i] = *(const uint4*)p;
    }
    __syncthreads();   // previous tile fully consumed
#pragma unroll
    for (int i = 0; i < 6; i++) {
      int idx = i * 256 + tid;
      int row = idx >> 4, seg = (idx & 15) * 8;
      f16* dst = (row < 48) ? &As[row][seg] : &Bs[row - 48][seg];
      *(uint4*)dst = v[i];
    }
    __syncthreads();
    int kk = wave * 32;
    half8 af[3], bf[3];
#pragma unroll
    for (int i = 0; i < 3; i++) {
      af[i] = *(const half8*)&As[i * 16 + l15][kk + quad * 8];
      bf[i] = *(const half8*)&Bs[i * 16 + l15][kk + quad * 8];
    }
#pragma unroll
    for (int mi = 0; mi < 3; mi++)
#pragma unroll
      for (int ni = 0; ni < 3; ni++)
        acc[mi][ni] = __builtin_amdgcn_mfma_f32_16x16x32_f16(af[mi], bf[ni], acc[mi][ni], 0, 0, 0);
    if (tid < 192) {
      const f16* r = (nrow < 48) ? &As[nrow][nhalf * 64] : &Bs[nrow - 48][nhalf * 64];
#pragma unroll
      for (int e = 0; e < 8; e++) {
        U4H8 tt; tt.u = *(const uint4*)(r + e * 8);
#pragma unroll
        for (int j = 0; j < 8; j++) { float x = (float)tt.h[j]; ns_acc += x * x; }
      }
    }
  }
  __syncthreads();
  for (int w = 0; w < 4; w++) {
    if (wave == w) {
#pragma unroll
      for (int mi = 0; mi < 3; mi++)
#pragma unroll
        for (int ni = 0; ni < 3; ni++)
#pragma unroll
          for (int r = 0; r < 4; r++)
            Gacc[mi * 16 + quad * 4 + r][ni * 16 + l15] += acc[mi][ni][r];
    }
    __syncthreads();
  }
  float* base = gram + ((size_t)b * 4 + h) * 4800;
  float* G = base + pair * 2304;
  for (int i = tid; i < 2304; i += 256)
    atomicAdd(G + i, Gacc[i / 48][i - (i / 48) * 48]);
  if (tid < 192) {
    int slot = pair * 2 + (nrow >= 48 ? 1 : 0);
    int ch = (nrow >= 48) ? (nrow - 48) : nrow;
    atomicAdd(base + 4608 + slot * 48 + ch, ns_acc);
  }
}

// ---------------- softmax over 48 cols of 16 tiny matrices ------------------
__global__ void softmax_kernel(const float* __restrict__ gram, const float* __restrict__ temp,
                               float* __restrict__ att) {
  int id = blockIdx.x;                    // 16 = b*8 + h*2 + pr
  int b = id >> 3, h = (id >> 1) & 3, pr = id & 1;
  int tid = threadIdx.x;                  // 64
  __shared__ float srk[48];
  const float* base = gram + ((size_t)b * 4 + h) * 4800;
  const float* G  = base + pr * 2304;
  const float* nq = base + 4608 + (pr ? 96 : 0);
  const float* nk = base + 4608 + (pr ? 144 : 48);
  if (tid < 48) srk[tid] = 1.f / fmaxf(sqrtf(nk[tid]), 1e-12f);
  __syncthreads();
  if (tid < 48) {
    float rq = 1.f / fmaxf(sqrtf(nq[tid]), 1e-12f);
    float T = temp[h];
    float s[48], mx = -1e30f;
#pragma unroll
    for (int d = 0; d < 48; d++) { s[d] = T * G[tid * 48 + d] * rq * srk[d]; mx = fmaxf(mx, s[d]); }
    float sum = 0.f;
#pragma unroll
    for (int d = 0; d < 48; d++) { s[d] = __expf(s[d] - mx); sum += s[d]; }
    float inv = 1.f / sum;
    float* A = att + (((size_t)b * 2 + pr) * 4 + h) * 2304 + tid * 48;
#pragma unroll
    for (int d = 0; d < 48; d++) A[d] = s[d] * inv;
  }
}

// ---------------- M_cat = [W_fc*blkdiag(A_raw) | W_fc*blkdiag(A_rgb)] -------
__global__ __launch_bounds__(256) void mbuild_kernel(const float* __restrict__ wfc,
                                                     const float* __restrict__ att,
                                                     f16* __restrict__ mcat) {
  int e = blockIdx.x * 256 + threadIdx.x;
  if (e >= 147456) return;
  int b = e / 73728, r = e - b * 73728;
  int o = r / 384, j = r - o * 384;
  int pr = j / 192, jj = j - pr * 192;
  int h = jj / 48, d = jj - h * 48;
  const float* A = att + (((size_t)b * 2 + pr) * 4 + h) * 2304 + d;
  const float* w = wfc + o * 192 + h * 48;
  float s = 0.f;
  for (int c = 0; c < 48; c++) s += w[c] * A[c * 48];
  mcat[(size_t)b * 73728 + o * 384 + j] = (f16)s;
}

// ---------------- fused pshuffle -> dwconv5x5 & dil-3x3 -> mish -> punshuffle
// Register-tiled: the dilated-3x3 taps and all 25 shuffled-5x5 taps for one
// output pixel live in the same 3x3 original-pixel neighborhood (8 subch).
// 9 ds_read_b128 per thread, convert once, then pure FMA. Cheap exact mish:
// tanh(softplus(x)) = (t^2+2t)/(t^2+2t+2), t = e^x.
__global__ __launch_bounds__(256) void dwmish_kernel(const f16* __restrict__ hid,
                                                     const float* __restrict__ w5,
                                                     const float* __restrict__ w3,
                                                     f16* __restrict__ u) {
  __shared__ f16 sx[324][8];   // 18x18 pixels x (4 x1-subch + 4 x2-subch)
  int tid = threadIdx.x;
  int c = blockIdx.y, b = blockIdx.z;
  int ti0 = (blockIdx.x >> 3) * 16, tj0 = (blockIdx.x & 7) * 16;
  const float* wp5 = w5 + c * 25;   // block-uniform -> s_load
  const float* wp3 = w3 + c * 9;
  for (int pix = tid; pix < 324; pix += 256) {
    int pi = pix / 18, pj = pix - pi * 18;
    int gi = ti0 - 1 + pi, gj = tj0 - 1 + pj;
    uint2 v0 = {0u, 0u}, v1 = {0u, 0u};
    if (gi >= 0 && gi < 128 && gj >= 0 && gj < 128) {
      const f16* base = hid + ((size_t)b * HW + gi * 128 + gj) * 1024 + c * 4;
      v0 = *(const uint2*)base;
      v1 = *(const uint2*)(base + 512);
    }
    uint4 vv = {v0.x, v0.y, v1.x, v1.y};
    *(uint4*)&sx[pix][0] = vv;
  }
  __syncthreads();
  int ti = tid >> 4, tj = tid & 15;
  U4H8 px[3][3];
#pragma unroll
  for (int dy = 0; dy < 3; dy++)
#pragma unroll
    for (int dx = 0; dx < 3; dx++)
      px[dy][dx].u = *(const uint4*)&sx[(ti + dy) * 18 + tj + dx][0];
  float xf[3][3][8];
#pragma unroll
  for (int dy = 0; dy < 3; dy++)
#pragma unroll
    for (int dx = 0; dx < 3; dx++)
#pragma unroll
      for (int e = 0; e < 8; e++) xf[dy][dx][e] = (float)px[dy][dx].h[e];
  U2H4 res;
#pragma unroll
  for (int pq = 0; pq < 4; pq++) {
    int p = pq >> 1, q = pq & 1;
    float a2 = 0.f;
#pragma unroll
    for (int ky = 0; ky < 3; ky++)
#pragma unroll
      for (int kx = 0; kx < 3; kx++)
        a2 += wp3[ky * 3 + kx] * xf[ky][kx][4 + pq];
    float a1 = 0.f;
#pragma unroll
    for (int dy = -2; dy <= 2; dy++)
#pragma unroll
      for (int dx = -2; dx <= 2; dx++) {
        int s = p + dy, t2 = q + dx;
        int di = s >> 1, ps_ = s & 1;
        int dj = t2 >> 1, qs_ = t2 & 1;
        a1 += wp5[(dy + 2) * 5 + dx + 2] * xf[1 + di][1 + dj][ps_ * 2 + qs_];
      }
    float t = __expf(fminf(a2, 20.f));
    float num = t * (t + 2.f);
    float m = a2 * num * __builtin_amdgcn_rcpf(num + 2.f);
    res.h[pq] = (f16)(m * a1);
  }
  int gi = ti0 + ti, gj = tj0 + tj;
  *(uint2*)(u + ((size_t)b * HW + gi * 128 + gj) * 512 + c * 4) = res.u;
}

// ---------------------------------------------------------------------------
extern "C" void kernel_launch(void* const* d_in, const int* in_sizes, int n_in,
                              void* d_out, int out_size, void* d_ws, size_t ws_size,
                              hipStream_t stream) {
  const float* F_raw    = (const float*)d_in[0];
  const float* F_Y      = (const float*)d_in[1];
  const float* temp     = (const float*)d_in[2];
  const float* w_raw_kv = (const float*)d_in[3];
  const float* w_raw_q  = (const float*)d_in[4];
  const float* w_rgb_kv = (const float*)d_in[5];
  const float* w_rgb_q  = (const float*)d_in[6];
  const float* w_g1     = (const float*)d_in[7];
  const float* b_g1     = (const float*)d_in[8];
  const float* w_g2     = (const float*)d_in[9];
  const float* b_g2     = (const float*)d_in[10];
  const float* w_fc     = (const float*)d_in[11];
  const float* b_fc     = (const float*)d_in[12];
  const float* w_pin    = (const float*)d_in[13];
  const float* w_dw5    = (const float*)d_in[14];
  const float* w_dwd    = (const float*)d_in[15];
  const float* w_pout   = (const float*)d_in[16];
  char* ws = (char*)d_ws;
  float* dout = (float*)d_out;

  const size_t O_FCAT  = 0;            // 25,165,824  f16 Fcat (NPIX x 384)
  const size_t O_QKV0  = 25165824;     // 37,748,736  f16 raw [k|v|q] (NPIX x 576)
  const size_t O_QKV1  = 62914560;     // 37,748,736  f16 rgb
  const size_t O_ALPHA = 100663296;    // 131,072     fp32 alpha pre-sigmoid
  const size_t O_GRAM  = 100794368;    // 153,600     fp32 grams+normsq
  const size_t O_ATT   = 100947968;    // 147,456     fp32 softmaxed attn
  const size_t O_MCAT  = 101095424;    // 294,912     f16 M_cat (2 x 192 x 384)
  const size_t O_WB    = 101390336;    // 1,622,016   f16 converted weights
  const size_t O_OUTPM = 103012352;    // 25,165,824  fp32 out pixel-major
  const size_t O_QKT   = 103012352;    // 50,331,648  f16 qkT (dead before ctx gemm)
  const size_t O_NORM  = 128178176;    // 12,582,912  f16 cnorm(out)
  const size_t O_HID   = O_QKV0;       // 67,108,864  f16 hidden (reuses dead qkv)
  const size_t O_U     = 140761088;    // 33,554,432  f16 u  (ends 174,315,520)
  if (ws_size < 174315520) return;

  f16* wb      = (f16*)(ws + O_WB);
  f16* wb_kvR  = wb;
  f16* wb_qR   = wb + 73728;
  f16* wb_kvG  = wb + 110592;
  f16* wb_qG   = wb + 184320;
  f16* wb_g1   = wb + 221184;
  f16* wb_pin  = wb + 516096;
  f16* wb_pout = wb + 712704;

  WConvArgs wa;
  wa.src[0] = w_raw_kv; wa.dst[0] = wb_kvR;  wa.n[0] = 73728;
  wa.src[1] = w_raw_q;  wa.dst[1] = wb_qR;   wa.n[1] = 36864;
  wa.src[2] = w_rgb_kv; wa.dst[2] = wb_kvG;  wa.n[2] = 73728;
  wa.src[3] = w_rgb_q;  wa.dst[3] = wb_qG;   wa.n[3] = 36864;
  wa.src[4] = w_g1;     wa.dst[4] = wb_g1;   wa.n[4] = 294912;
  wa.src[5] = w_pin;    wa.dst[5] = wb_pin;  wa.n[5] = 196608;
  wa.src[6] = w_pout;   wa.dst[6] = wb_pout; wa.n[6] = 98304;
  wconv_kernel<<<dim3(16, 7), 256, 0, stream>>>(wa);

  hipMemsetAsync(ws + O_ALPHA, 0, 131072 + 153600, stream);

  f16* fcat = (f16*)(ws + O_FCAT);
  cnorm_in_kernel<<<512, 256, 0, stream>>>(F_raw, fcat, 0);
  cnorm_in_kernel<<<512, 256, 0, stream>>>(F_Y, fcat, 192);

  {  // qkv raw + rgb
    GArgs a = {};
    a.A = fcat; a.lda = 384; a.aoff = 0;
    a.B1 = wb_kvR; a.B2 = wb_qR; a.b1rows = 384; a.Nout = 576; a.K = 192; a.bStride = 0;
    a.outH = (f16*)(ws + O_QKV0); a.ldo = 576;
    gemm_k<0><<<dim3(5, 256), 256, 0, stream>>>(a);
    a.aoff = 192; a.B1 = wb_kvG; a.B2 = wb_qG; a.outH = (f16*)(ws + O_QKV1);
    gemm_k<0><<<dim3(5, 256), 256, 0, stream>>>(a);
  }
  {  // g1 gemm with gelu + alpha row-reduction
    GArgs a = {};
    a.A = fcat; a.lda = 384; a.aoff = 0;
    a.B1 = wb_g1; a.B2 = wb_g1; a.b1rows = 768; a.Nout = 768; a.K = 384; a.bStride = 0;
    a.bg1 = b_g1; a.wg2 = w_g2; a.alpha_acc = (float*)(ws + O_ALPHA);
    gemm_k<1><<<dim3(6, 256), 256, 0, stream>>>(a);
  }
  qk_transpose_kernel<<<dim3(64, 6, 4), 256, 0, stream>>>((const f16*)(ws + O_QKV0),
                                                          (const f16*)(ws + O_QKV1),
                                                          (f16*)(ws + O_QKT));
  gram_mfma_kernel<<<dim3(16, 8, 2), 256, 0, stream>>>((const f16*)(ws + O_QKT),
                                                       (float*)(ws + O_GRAM));
  softmax_kernel<<<16, 64, 0, stream>>>((const float*)(ws + O_GRAM), temp, (float*)(ws + O_ATT));
  mbuild_kernel<<<576, 256, 0, stream>>>(w_fc, (const float*)(ws + O_ATT), (f16*)(ws + O_MCAT));
  {  // ctx + fc + residual -> outpm fp32
    GArgs a = {};
    a.B1 = (const f16*)(ws + O_MCAT); a.B2 = (const f16*)(ws + O_MCAT);
    a.b1rows = 192; a.Nout = 192; a.K = 384; a.bStride = 73728;
    a.vraw = (const f16*)(ws + O_QKV0); a.vrgb = (const f16*)(ws + O_QKV1);
    a.alpha_pre = (float*)(ws + O_ALPHA); a.bg2 = b_g2;
    a.bfc = b_fc; a.fcat = fcat; a.outpm = (float*)(ws + O_OUTPM);
    gemm_k<2><<<dim3(2, 256), 256, 0, stream>>>(a);
  }
  norm_pm_kernel<<<512, 256, 0, stream>>>((const float*)(ws + O_OUTPM), (f16*)(ws + O_NORM));
  {  // pin gemm -> hidden
    GArgs a = {};
    a.A = (const f16*)(ws + O_NORM); a.lda = 192; a.aoff = 0;
    a.B1 = wb_pin; a.B2 = wb_pin; a.b1rows = 1024; a.Nout = 1024; a.K = 192; a.bStride = 0;
    a.outH = (f16*)(ws + O_HID); a.ldo = 1024;
    gemm_k<0><<<dim3(8, 256), 256, 0, stream>>>(a);
  }
  dwmish_kernel<<<dim3(64, 128, 2), 256, 0, stream>>>((const f16*)(ws + O_HID), w_dw5, w_dwd,
                                                      (f16*)(ws + O_U));
  {  // pout gemm + residual -> d_out (NCHW fp32)
    GArgs a = {};
    a.A = (const f16*)(ws + O_U); a.lda = 512; a.aoff = 0;
    a.B1 = wb_pout; a.B2 = wb_pout; a.b1rows = 192; a.Nout = 192; a.K = 512; a.bStride = 0;
    a.outpm_r = (const float*)(ws + O_OUTPM); a.dout = dout;
    gemm_k<3><<<dim3(2, 256), 256, 0, stream>>>(a);
  }
}

// Round 5
// 445.983 us; speedup vs baseline: 2.1590x; 1.4235x over previous
//
#include <hip/hip_runtime.h>
#include <cstdint>
#include <cstddef>

// ---------------------------------------------------------------------------
// DynamicReflectionAttention fused pipeline for MI355X (gfx950)
// Activations pixel-major fp16. GEMMs: 128x128 tile, BK=64, async
// global_load_lds staging with XOR-swizzled LDS, MFMA 16x16x32 f16.
// NOTE: shared memory is declared ONCE per __global__ kernel and passed into
// gemm2_body — three inlined bodies must not each allocate 33 KB of LDS.
// ---------------------------------------------------------------------------

typedef _Float16 f16;
using half8  = __attribute__((ext_vector_type(8))) _Float16;
using float4v = __attribute__((ext_vector_type(4))) float;

#define HW    16384
#define NPIX  32768

union U4H8 { uint4 u; f16 h[8]; };
union U2H4 { uint2 u; f16 h[4]; };

// ---------------- weight fp32 -> fp16 convert (7 tensors, one launch) -------
struct WConvArgs { const float* src[7]; f16* dst[7]; int n[7]; };
__global__ __launch_bounds__(256) void wconv_kernel(WConvArgs a) {
  int t = blockIdx.y;
  const float* s = a.src[t]; f16* d = a.dst[t]; int n = a.n[t];
  for (int i = blockIdx.x * 256 + threadIdx.x; i < n; i += gridDim.x * 256)
    d[i] = (f16)s[i];
}

// ---------------- cnorm of NCHW fp32 input -> pixel-major f16 Fcat ----------
__global__ __launch_bounds__(256) void cnorm_in_kernel(const float* __restrict__ x,
                                                       f16* __restrict__ fcat, int zoff) {
  __shared__ float tile[64][193];
  __shared__ float rsum[64][4], rsq[64][4], mm[64], rr[64];
  int tid = threadIdx.x;
  int P0 = blockIdx.x * 64;
  int b  = P0 >> 14;
  int p0 = P0 & (HW - 1);
  for (int i = tid; i < 64 * 192; i += 256) {
    int c = i >> 6, pp = i & 63;
    tile[pp][c] = x[((size_t)(b * 192 + c)) * HW + p0 + pp];
  }
  __syncthreads();
  {
    int pp = tid >> 2, q = tid & 3;
    float s = 0.f, s2 = 0.f;
    for (int c = q * 48; c < q * 48 + 48; c++) { float v = tile[pp][c]; s += v; s2 += v * v; }
    rsum[pp][q] = s; rsq[pp][q] = s2;
  }
  __syncthreads();
  if (tid < 64) {
    float s  = rsum[tid][0] + rsum[tid][1] + rsum[tid][2] + rsum[tid][3];
    float s2 = rsq[tid][0] + rsq[tid][1] + rsq[tid][2] + rsq[tid][3];
    float mu = s * (1.f / 192.f);
    float var = s2 * (1.f / 192.f) - mu * mu;
    mm[tid] = mu; rr[tid] = rsqrtf(var + 1e-5f);
  }
  __syncthreads();
  for (int i = tid; i < 64 * 192; i += 256) {
    int pp = i / 192, c = i - pp * 192;
    float v = (tile[pp][c] - mm[pp]) * rr[pp];
    fcat[(size_t)(P0 + pp) * 384 + zoff + c] = (f16)v;
  }
}

// ---------------- cnorm of pixel-major fp32 -> pixel-major f16 --------------
__global__ __launch_bounds__(256) void norm_pm_kernel(const float* __restrict__ xpm,
                                                      f16* __restrict__ outn) {
  __shared__ float tile[64][193];
  __shared__ float rsum[64][4], rsq[64][4], mm[64], rr[64];
  int tid = threadIdx.x;
  int P0 = blockIdx.x * 64;
  for (int i = tid; i < 64 * 192; i += 256) {
    int pp = i / 192, c = i - pp * 192;
    tile[pp][c] = xpm[(size_t)(P0 + pp) * 192 + c];
  }
  __syncthreads();
  {
    int pp = tid >> 2, q = tid & 3;
    float s = 0.f, s2 = 0.f;
    for (int c = q * 48; c < q * 48 + 48; c++) { float v = tile[pp][c]; s += v; s2 += v * v; }
    rsum[pp][q] = s; rsq[pp][q] = s2;
  }
  __syncthreads();
  if (tid < 64) {
    float s  = rsum[tid][0] + rsum[tid][1] + rsum[tid][2] + rsum[tid][3];
    float s2 = rsq[tid][0] + rsq[tid][1] + rsq[tid][2] + rsq[tid][3];
    float mu = s * (1.f / 192.f);
    float var = s2 * (1.f / 192.f) - mu * mu;
    mm[tid] = mu; rr[tid] = rsqrtf(var + 1e-5f);
  }
  __syncthreads();
  for (int i = tid; i < 64 * 192; i += 256) {
    int pp = i / 192, c = i - pp * 192;
    outn[(size_t)(P0 + pp) * 192 + c] = (f16)((tile[pp][c] - mm[pp]) * rr[pp]);
  }
}

// ---------------- async-staged 128x128xBK64 MFMA GEMM body ------------------
// MODE 0: plain f16 store        (qkv, pin)
// MODE 1: gelu + w_g2 row-reduction into alpha_acc atomics (g1, no store)
// MODE 2: A = [alpha*v_raw ; (1-alpha)*v_rgb] scaled pre-MFMA; epi -> outpm
// MODE 3: epi: + outpm residual, LDS-transpose, store NCHW fp32 d_out (pout)
struct G2Args {
  const f16* A; long lda; long aoff;
  const f16* B1; const f16* B2; int b1rows; int Nout; int K; long bStride;
  f16* outH; long ldo;
  const float* bfc; const f16* fcat; float* outpm;
  const float* bg1; const float* wg2; float* alpha_acc;
  const f16* vraw; const f16* vrgb; const float* alpha_pre; const float* bg2;
  const float* outpm_r; float* dout;
};

#define GEMM_SMEM_BYTES 33280

template <int MODE>
__device__ __forceinline__ void gemm2_body(const G2Args& g, int bx, int by, char* smem) {
  f16 (*As)[64] = (f16(*)[64])smem;            // 128 x 64 f16 = 16 KB (unpadded)
  f16 (*Bs)[64] = (f16(*)[64])(smem + 16384);  // 16 KB
  float* salpha = (float*)(smem + 32768);      // 512 B (MODE 2)

  int tid = threadIdx.x;
  int P0 = by * 128;
  int n0 = bx * 128;
  int wave = tid >> 6, lane = tid & 63, l15 = lane & 15, quad = lane >> 4;
  int m_off = (wave >> 1) * 64, n_off = (wave & 1) * 64;
  int lrow = lane >> 3, loct = lane & 7;
  const f16* B1 = g.B1 + (size_t)(P0 >> 14) * g.bStride;

  f16 hsa[4], hsb[4];
  if (MODE == 2) {
    if (tid < 128) {
      float a = g.alpha_pre[P0 + tid] + g.bg2[0];
      salpha[tid] = 1.f / (1.f + __expf(-a));
    }
    __syncthreads();
#pragma unroll
    for (int i = 0; i < 4; i++) {
      float s0 = salpha[m_off + i * 16 + l15];
      hsa[i] = (f16)s0; hsb[i] = (f16)(1.f - s0);
    }
  }

  float4v acc[4][4];
#pragma unroll
  for (int i = 0; i < 4; i++)
#pragma unroll
    for (int j = 0; j < 4; j++) acc[i][j] = (float4v){0.f, 0.f, 0.f, 0.f};

  int nkt = g.K >> 6;
  for (int kt = 0; kt < nkt; kt++) {
    int k0 = kt << 6;
    // ---- async stage: wave w covers rows [w*32, w*32+32) of A and B tiles.
    // LDS side fixed (base + lane*16); swizzle applied on the GLOBAL side:
    // LDS[r][oct] holds global[r][oct ^ (r&7)] -> conflict-free ds_read_b128.
#pragma unroll
    for (int j = 0; j < 4; j++) {
      int rbase = wave * 32 + j * 8;
      int r = rbase + lrow;
      int oct = loct ^ (r & 7);
      const f16* ga;
      if (MODE == 2) {
        const f16* base = (k0 < 192) ? (g.vraw + 192 + k0) : (g.vrgb + k0);
        ga = base + (size_t)(P0 + r) * 576 + oct * 8;
      } else {
        ga = g.A + (size_t)(P0 + r) * g.lda + g.aoff + k0 + oct * 8;
      }
      __builtin_amdgcn_global_load_lds((const __attribute__((address_space(1))) void*)ga,
                                       (__attribute__((address_space(3))) void*)&As[rbase][0],
                                       16, 0, 0);
    }
#pragma unroll
    for (int j = 0; j < 4; j++) {
      int rbase = wave * 32 + j * 8;
      int r = rbase + lrow;
      int oct = loct ^ (r & 7);
      int n = n0 + r;
      int nc = (n >= g.Nout) ? (g.Nout - 1) : n;   // clamp; junk cols never stored
      const f16* gb = (nc < g.b1rows)
                          ? (B1 + (size_t)nc * g.K + k0 + oct * 8)
                          : (g.B2 + (size_t)(nc - g.b1rows) * g.K + k0 + oct * 8);
      __builtin_amdgcn_global_load_lds((const __attribute__((address_space(1))) void*)gb,
                                       (__attribute__((address_space(3))) void*)&Bs[rbase][0],
                                       16, 0, 0);
    }
    __syncthreads();   // drains vmcnt -> DMA complete
#pragma unroll
    for (int ks = 0; ks < 2; ks++) {
      half8 af[4], bf[4];
#pragma unroll
      for (int i = 0; i < 4; i++) {
        int ra = m_off + i * 16 + l15;
        af[i] = *(const half8*)&As[ra][(((ks * 4 + quad) ^ (l15 & 7))) * 8];
        int rb = n_off + i * 16 + l15;
        bf[i] = *(const half8*)&Bs[rb][(((ks * 4 + quad) ^ (l15 & 7))) * 8];
      }
      if (MODE == 2) {
#pragma unroll
        for (int i = 0; i < 4; i++) {
          f16 s = (k0 < 192) ? hsa[i] : hsb[i];
          half8 sv = {s, s, s, s, s, s, s, s};
          af[i] *= sv;
        }
      }
#pragma unroll
      for (int mi = 0; mi < 4; mi++)
#pragma unroll
        for (int ni = 0; ni < 4; ni++)
          acc[mi][ni] = __builtin_amdgcn_mfma_f32_16x16x32_f16(af[mi], bf[ni], acc[mi][ni], 0, 0, 0);
    }
    __syncthreads();
  }

  if (MODE == 0) {
#pragma unroll
    for (int mi = 0; mi < 4; mi++) {
      int row = P0 + m_off + mi * 16 + quad * 4;
#pragma unroll
      for (int ni = 0; ni < 4; ni++) {
        int gcol = n0 + n_off + ni * 16 + l15;
        if (gcol < g.Nout) {
#pragma unroll
          for (int r = 0; r < 4; r++)
            g.outH[(size_t)(row + r) * g.ldo + gcol] = (f16)acc[mi][ni][r];
        }
      }
    }
  } else if (MODE == 1) {
    float bg[4], wg[4];
#pragma unroll
    for (int ni = 0; ni < 4; ni++) {
      int gcol = n0 + n_off + ni * 16 + l15;
      bg[ni] = g.bg1[gcol]; wg[ni] = g.wg2[gcol];
    }
    float psum[4][4];
#pragma unroll
    for (int mi = 0; mi < 4; mi++)
#pragma unroll
      for (int r = 0; r < 4; r++) psum[mi][r] = 0.f;
#pragma unroll
    for (int mi = 0; mi < 4; mi++)
#pragma unroll
      for (int ni = 0; ni < 4; ni++)
#pragma unroll
        for (int r = 0; r < 4; r++) {
          float xx = acc[mi][ni][r] + bg[ni];
          float z = 0.7978845608f * (xx + 0.044715f * xx * xx * xx);
          float zc = fminf(fmaxf(z, -10.f), 10.f);
          float t = __expf(2.f * zc);
          float th = (t - 1.f) * __builtin_amdgcn_rcpf(t + 1.f);
          float ge = 0.5f * xx * (1.f + th);
          psum[mi][r] += ge * wg[ni];
        }
#pragma unroll
    for (int s = 1; s < 16; s <<= 1)
#pragma unroll
      for (int mi = 0; mi < 4; mi++)
#pragma unroll
        for (int r = 0; r < 4; r++) psum[mi][r] += __shfl_xor(psum[mi][r], s, 64);
    if (l15 == 0) {
#pragma unroll
      for (int mi = 0; mi < 4; mi++)
#pragma unroll
        for (int r = 0; r < 4; r++)
          atomicAdd(&g.alpha_acc[P0 + m_off + mi * 16 + quad * 4 + r], psum[mi][r]);
    }
  } else if (MODE == 2) {
#pragma unroll
    for (int mi = 0; mi < 4; mi++) {
      int prow = P0 + m_off + mi * 16 + quad * 4;
#pragma unroll
      for (int ni = 0; ni < 4; ni++) {
        int gcol = n0 + n_off + ni * 16 + l15;
        if (gcol < 192) {
#pragma unroll
          for (int r = 0; r < 4; r++) {
            size_t P = (size_t)(prow + r);
            float v = acc[mi][ni][r] + g.bfc[gcol] +
                      (float)g.fcat[P * 384 + gcol] + (float)g.fcat[P * 384 + 192 + gcol];
            g.outpm[P * 192 + gcol] = v;
          }
        }
      }
    }
  } else {  // MODE 3
#pragma unroll
    for (int mi = 0; mi < 4; mi++) {
      int prow = P0 + m_off + mi * 16 + quad * 4;
#pragma unroll
      for (int ni = 0; ni < 4; ni++) {
        int gcol = n0 + n_off + ni * 16 + l15;
        if (gcol < 192) {
#pragma unroll
          for (int r = 0; r < 4; r++)
            acc[mi][ni][r] += g.outpm_r[(size_t)(prow + r) * 192 + gcol];
        }
      }
    }
    float (*bounce)[129] = (float(*)[129])smem;  // 32 x 129 fp32 = 16512 B
    for (int cg = 0; cg < 4; cg++) {
      __syncthreads();
      if ((wave & 1) == (cg >> 1)) {
#pragma unroll
        for (int nn = 0; nn < 2; nn++) {
          int ni = (cg & 1) * 2 + nn;
          int lc = nn * 16 + l15;
#pragma unroll
          for (int mi = 0; mi < 4; mi++)
#pragma unroll
            for (int r = 0; r < 4; r++)
              bounce[lc][m_off + mi * 16 + quad * 4 + r] = acc[mi][ni][r];
        }
      }
      __syncthreads();
      int c = tid >> 3, ps = (tid & 7) * 16;
      int gc = n0 + cg * 32 + c;
      if (gc < 192) {
        int b = P0 >> 14, p = (P0 & (HW - 1)) + ps;
        float* dst = g.dout + ((size_t)b * 192 + gc) * HW + p;
#pragma unroll
        for (int i = 0; i < 16; i++) dst[i] = bounce[c][ps + i];
      }
    }
  }
}

template <int MODE>
__global__ __launch_bounds__(256) void gemm2_k(G2Args g) {
  __shared__ __align__(16) char smem[GEMM_SMEM_BYTES];
  gemm2_body<MODE>(g, (int)blockIdx.y, (int)blockIdx.x, smem);  // x = m-tile (fast)
}

// qkv-raw (5 n-tiles) + qkv-rgb (5) + g1 (6), all reading fcat: one dispatch.
// ONE shared buffer for all three inlined bodies.
__global__ __launch_bounds__(256) void gemm_fused_kernel(G2Args j0, G2Args j1, G2Args j2) {
  __shared__ __align__(16) char smem[GEMM_SMEM_BYTES];
  int id = blockIdx.x;
  if (id < 1280)      gemm2_body<0>(j0, id / 256, id & 255, smem);
  else if (id < 2560) gemm2_body<0>(j1, (id - 1280) / 256, id & 255, smem);
  else                gemm2_body<1>(j2, (id - 2560) / 256, id & 255, smem);
}

// ---------------- qkv pixel-major -> channel-major transpose (q,k only) -----
__global__ __launch_bounds__(256) void qk_transpose_kernel(const f16* __restrict__ qkvR,
                                                           const f16* __restrict__ qkvG,
                                                           f16* __restrict__ qkT) {
  __shared__ f16 T[64][264];
  int tid = threadIdx.x;
  int p0 = blockIdx.x * 256;
  int g  = blockIdx.y;
  int t  = blockIdx.z >> 1, b = blockIdx.z & 1;
  const f16* src = t ? qkvG : qkvR;
  int col0 = (g < 3) ? g * 64 : g * 64 + 192;
#pragma unroll
  for (int i = 0; i < 4; i++) {
    int idx = i * 256 + tid;
    int pp = idx >> 3, c8 = (idx & 7) * 8;
    const f16* s0 = src + ((size_t)(b * HW + p0 + 2 * pp)) * 576 + col0 + c8;
    uint4 v0 = *(const uint4*)s0;
    uint4 v1 = *(const uint4*)(s0 + 576);
    const unsigned* a = (const unsigned*)&v0;
    const unsigned* c = (const unsigned*)&v1;
#pragma unroll
    for (int w = 0; w < 4; w++) {
      unsigned lo = (a[w] & 0xffffu) | (c[w] << 16);
      unsigned hi = (a[w] >> 16) | (c[w] & 0xffff0000u);
      *(unsigned*)&T[c8 + 2 * w][2 * pp]     = lo;
      *(unsigned*)&T[c8 + 2 * w + 1][2 * pp] = hi;
    }
  }
  __syncthreads();
  size_t obase = ((size_t)(t * 2 + b) * 384 + g * 64) * 16384 + p0;
#pragma unroll
  for (int i = 0; i < 8; i++) {
    int idx = i * 256 + tid;
    int row = idx >> 5, p8 = (idx & 31) * 8;
    *(uint4*)(qkT + obase + (size_t)row * 16384 + p8) = *(const uint4*)&T[row][p8];
  }
}

// ---------------- split-K MFMA Gram + sum-of-squares ------------------------
__global__ __launch_bounds__(256) void gram_mfma_kernel(const f16* __restrict__ qkT,
                                                        float* __restrict__ gram) {
  __shared__ __align__(16) f16 As[48][136];
  __shared__ __align__(16) f16 Bs[48][136];
  __shared__ float Gacc[48][49];
  int tid = threadIdx.x;
  int chunk = blockIdx.x;
  int h = blockIdx.y >> 1, pair = blockIdx.y & 1;
  int b = blockIdx.z;
  int tA = pair ? 0 : 1, tB = pair ? 1 : 0;
  const f16* Abase = qkT + ((size_t)(tA * 2 + b) * 384 + 192 + 48 * h) * 16384;
  const f16* Bbase = qkT + ((size_t)(tB * 2 + b) * 384 + 48 * h) * 16384;
  for (int i = tid; i < 48 * 49; i += 256) ((float*)Gacc)[i] = 0.f;
  int wave = tid >> 6, lane = tid & 63, l15 = lane & 15, quad = lane >> 4;
  float4v acc[3][3];
#pragma unroll
  for (int i = 0; i < 3; i++)
#pragma unroll
    for (int j = 0; j < 3; j++) acc[i][j] = (float4v){0.f, 0.f, 0.f, 0.f};
  float ns_acc = 0.f;
  int nrow = tid >> 1, nhalf = tid & 1;

  for (int stage = 0; stage < 8; stage++) {
    int k0 = chunk * 1024 + stage * 128;
    uint4 v[6];
#pragma unroll
    for (int i = 0; i < 6; i++) {
      int idx = i * 256 + tid;
      int row = idx >> 4, seg = (idx & 15) * 8;
      const f16* p = (row < 48) ? (Abase + (size_t)row * 16384 + k0 + seg)
                                : (Bbase + (size_t)(row - 48) * 16384 + k0 + seg);
      v[i] = *(const uint4*)p;
    }
    __syncthreads();
#pragma unroll
    for (int i = 0; i < 6; i++) {
      int idx = i * 256 + tid;
      int row = idx >> 4, seg = (idx & 15) * 8;
      f16* dst = (row < 48) ? &As[row][seg] : &Bs[row - 48][seg];
      *(uint4*)dst = v[i];
    }
    __syncthreads();
    int kk = wave * 32;
    half8 af[3], bf[3];
#pragma unroll
    for (int i = 0; i < 3; i++) {
      af[i] = *(const half8*)&As[i * 16 + l15][kk + quad * 8];
      bf[i] = *(const half8*)&Bs[i * 16 + l15][kk + quad * 8];
    }
#pragma unroll
    for (int mi = 0; mi < 3; mi++)
#pragma unroll
      for (int ni = 0; ni < 3; ni++)
        acc[mi][ni] = __builtin_amdgcn_mfma_f32_16x16x32_f16(af[mi], bf[ni], acc[mi][ni], 0, 0, 0);
    if (tid < 192) {
      const f16* r = (nrow < 48) ? &As[nrow][nhalf * 64] : &Bs[nrow - 48][nhalf * 64];
#pragma unroll
      for (int e = 0; e < 8; e++) {
        U4H8 tt; tt.u = *(const uint4*)(r + e * 8);
#pragma unroll
        for (int j = 0; j < 8; j++) { float x = (float)tt.h[j]; ns_acc += x * x; }
      }
    }
  }
  __syncthreads();
  for (int w = 0; w < 4; w++) {
    if (wave == w) {
#pragma unroll
      for (int mi = 0; mi < 3; mi++)
#pragma unroll
        for (int ni = 0; ni < 3; ni++)
#pragma unroll
          for (int r = 0; r < 4; r++)
            Gacc[mi * 16 + quad * 4 + r][ni * 16 + l15] += acc[mi][ni][r];
    }
    __syncthreads();
  }
  float* base = gram + ((size_t)b * 4 + h) * 4800;
  float* G = base + pair * 2304;
  for (int i = tid; i < 2304; i += 256)
    atomicAdd(G + i, Gacc[i / 48][i - (i / 48) * 48]);
  if (tid < 192) {
    int slot = pair * 2 + (nrow >= 48 ? 1 : 0);
    int ch = (nrow >= 48) ? (nrow - 48) : nrow;
    atomicAdd(base + 4608 + slot * 48 + ch, ns_acc);
  }
}

// ---------------- softmax over 48 cols of 16 tiny matrices ------------------
__global__ void softmax_kernel(const float* __restrict__ gram, const float* __restrict__ temp,
                               float* __restrict__ att) {
  int id = blockIdx.x;
  int b = id >> 3, h = (id >> 1) & 3, pr = id & 1;
  int tid = threadIdx.x;
  __shared__ float srk[48];
  const float* base = gram + ((size_t)b * 4 + h) * 4800;
  const float* G  = base + pr * 2304;
  const float* nq = base + 4608 + (pr ? 96 : 0);
  const float* nk = base + 4608 + (pr ? 144 : 48);
  if (tid < 48) srk[tid] = 1.f / fmaxf(sqrtf(nk[tid]), 1e-12f);
  __syncthreads();
  if (tid < 48) {
    float rq = 1.f / fmaxf(sqrtf(nq[tid]), 1e-12f);
    float T = temp[h];
    float s[48], mx = -1e30f;
#pragma unroll
    for (int d = 0; d < 48; d++) { s[d] = T * G[tid * 48 + d] * rq * srk[d]; mx = fmaxf(mx, s[d]); }
    float sum = 0.f;
#pragma unroll
    for (int d = 0; d < 48; d++) { s[d] = __expf(s[d] - mx); sum += s[d]; }
    float inv = 1.f / sum;
    float* A = att + (((size_t)b * 2 + pr) * 4 + h) * 2304 + tid * 48;
#pragma unroll
    for (int d = 0; d < 48; d++) A[d] = s[d] * inv;
  }
}

// ---------------- M_cat = [W_fc*blkdiag(A_raw) | W_fc*blkdiag(A_rgb)] -------
__global__ __launch_bounds__(256) void mbuild_kernel(const float* __restrict__ wfc,
                                                     const float* __restrict__ att,
                                                     f16* __restrict__ mcat) {
  int e = blockIdx.x * 256 + threadIdx.x;
  if (e >= 147456) return;
  int b = e / 73728, r = e - b * 73728;
  int o = r / 384, j = r - o * 384;
  int pr = j / 192, jj = j - pr * 192;
  int h = jj / 48, d = jj - h * 48;
  const float* A = att + (((size_t)b * 2 + pr) * 4 + h) * 2304 + d;
  const float* w = wfc + o * 192 + h * 48;
  float s = 0.f;
  for (int c = 0; c < 48; c++) s += w[c] * A[c * 48];
  mcat[(size_t)b * 73728 + o * 384 + j] = (f16)s;
}

// ---------------- fused pshuffle -> dwconv5x5 & dil-3x3 -> mish -> punshuffle
__global__ __launch_bounds__(256) void dwmish_kernel(const f16* __restrict__ hid,
                                                     const float* __restrict__ w5,
                                                     const float* __restrict__ w3,
                                                     f16* __restrict__ u) {
  __shared__ f16 sx[324][8];
  int tid = threadIdx.x;
  int c = blockIdx.y, b = blockIdx.z;
  int ti0 = (blockIdx.x >> 3) * 16, tj0 = (blockIdx.x & 7) * 16;
  const float* wp5 = w5 + c * 25;
  const float* wp3 = w3 + c * 9;
  for (int pix = tid; pix < 324; pix += 256) {
    int pi = pix / 18, pj = pix - pi * 18;
    int gi = ti0 - 1 + pi, gj = tj0 - 1 + pj;
    uint2 v0 = {0u, 0u}, v1 = {0u, 0u};
    if (gi >= 0 && gi < 128 && gj >= 0 && gj < 128) {
      const f16* base = hid + ((size_t)b * HW + gi * 128 + gj) * 1024 + c * 4;
      v0 = *(const uint2*)base;
      v1 = *(const uint2*)(base + 512);
    }
    uint4 vv = {v0.x, v0.y, v1.x, v1.y};
    *(uint4*)&sx[pix][0] = vv;
  }
  __syncthreads();
  int ti = tid >> 4, tj = tid & 15;
  U4H8 px[3][3];
#pragma unroll
  for (int dy = 0; dy < 3; dy++)
#pragma unroll
    for (int dx = 0; dx < 3; dx++)
      px[dy][dx].u = *(const uint4*)&sx[(ti + dy) * 18 + tj + dx][0];
  float xf[3][3][8];
#pragma unroll
  for (int dy = 0; dy < 3; dy++)
#pragma unroll
    for (int dx = 0; dx < 3; dx++)
#pragma unroll
      for (int e = 0; e < 8; e++) xf[dy][dx][e] = (float)px[dy][dx].h[e];
  U2H4 res;
#pragma unroll
  for (int pq = 0; pq < 4; pq++) {
    int p = pq >> 1, q = pq & 1;
    float a2 = 0.f;
#pragma unroll
    for (int ky = 0; ky < 3; ky++)
#pragma unroll
      for (int kx = 0; kx < 3; kx++)
        a2 += wp3[ky * 3 + kx] * xf[ky][kx][4 + pq];
    float a1 = 0.f;
#pragma unroll
    for (int dy = -2; dy <= 2; dy++)
#pragma unroll
      for (int dx = -2; dx <= 2; dx++) {
        int s = p + dy, t2 = q + dx;
        int di = s >> 1, ps_ = s & 1;
        int dj = t2 >> 1, qs_ = t2 & 1;
        a1 += wp5[(dy + 2) * 5 + dx + 2] * xf[1 + di][1 + dj][ps_ * 2 + qs_];
      }
    float t = __expf(fminf(a2, 20.f));
    float num = t * (t + 2.f);
    float m = a2 * num * __builtin_amdgcn_rcpf(num + 2.f);
    res.h[pq] = (f16)(m * a1);
  }
  int gi = ti0 + ti, gj = tj0 + tj;
  *(uint2*)(u + ((size_t)b * HW + gi * 128 + gj) * 512 + c * 4) = res.u;
}

// ---------------------------------------------------------------------------
extern "C" void kernel_launch(void* const* d_in, const int* in_sizes, int n_in,
                              void* d_out, int out_size, void* d_ws, size_t ws_size,
                              hipStream_t stream) {
  const float* F_raw    = (const float*)d_in[0];
  const float* F_Y      = (const float*)d_in[1];
  const float* temp     = (const float*)d_in[2];
  const float* w_raw_kv = (const float*)d_in[3];
  const float* w_raw_q  = (const float*)d_in[4];
  const float* w_rgb_kv = (const float*)d_in[5];
  const float* w_rgb_q  = (const float*)d_in[6];
  const float* w_g1     = (const float*)d_in[7];
  const float* b_g1     = (const float*)d_in[8];
  const float* w_g2     = (const float*)d_in[9];
  const float* b_g2     = (const float*)d_in[10];
  const float* w_fc     = (const float*)d_in[11];
  const float* b_fc     = (const float*)d_in[12];
  const float* w_pin    = (const float*)d_in[13];
  const float* w_dw5    = (const float*)d_in[14];
  const float* w_dwd    = (const float*)d_in[15];
  const float* w_pout   = (const float*)d_in[16];
  char* ws = (char*)d_ws;
  float* dout = (float*)d_out;

  const size_t O_FCAT  = 0;            // 25,165,824  f16 Fcat (NPIX x 384)
  const size_t O_QKV0  = 25165824;     // f16 raw [k|v|q] (NPIX x 576)
  const size_t O_QKV1  = 62914560;     // f16 rgb
  const size_t O_ALPHA = 100663296;    // fp32 alpha pre-sigmoid
  const size_t O_GRAM  = 100794368;    // fp32 grams+normsq
  const size_t O_ATT   = 100947968;    // fp32 softmaxed attn
  const size_t O_MCAT  = 101095424;    // f16 M_cat (2 x 192 x 384)
  const size_t O_WB    = 101390336;    // f16 converted weights
  const size_t O_OUTPM = 103012352;    // fp32 out pixel-major
  const size_t O_QKT   = 103012352;    // f16 qkT (dead before ctx gemm)
  const size_t O_NORM  = 128178176;    // f16 cnorm(out)
  const size_t O_HID   = O_QKV0;       // f16 hidden (reuses dead qkv)
  const size_t O_U     = 140761088;    // f16 u
  if (ws_size < 174315520) return;

  f16* wb      = (f16*)(ws + O_WB);
  f16* wb_kvR  = wb;
  f16* wb_qR   = wb + 73728;
  f16* wb_kvG  = wb + 110592;
  f16* wb_qG   = wb + 184320;
  f16* wb_g1   = wb + 221184;
  f16* wb_pin  = wb + 516096;
  f16* wb_pout = wb + 712704;

  WConvArgs wa;
  wa.src[0] = w_raw_kv; wa.dst[0] = wb_kvR;  wa.n[0] = 73728;
  wa.src[1] = w_raw_q;  wa.dst[1] = wb_qR;   wa.n[1] = 36864;
  wa.src[2] = w_rgb_kv; wa.dst[2] = wb_kvG;  wa.n[2] = 73728;
  wa.src[3] = w_rgb_q;  wa.dst[3] = wb_qG;   wa.n[3] = 36864;
  wa.src[4] = w_g1;     wa.dst[4] = wb_g1;   wa.n[4] = 294912;
  wa.src[5] = w_pin;    wa.dst[5] = wb_pin;  wa.n[5] = 196608;
  wa.src[6] = w_pout;   wa.dst[6] = wb_pout; wa.n[6] = 98304;
  wconv_kernel<<<dim3(16, 7), 256, 0, stream>>>(wa);

  hipMemsetAsync(ws + O_ALPHA, 0, 131072 + 153600, stream);

  f16* fcat = (f16*)(ws + O_FCAT);
  cnorm_in_kernel<<<512, 256, 0, stream>>>(F_raw, fcat, 0);
  cnorm_in_kernel<<<512, 256, 0, stream>>>(F_Y, fcat, 192);

  {  // fused: qkv raw + qkv rgb + g1(gelu/alpha)
    G2Args j0 = {}, j1 = {}, j2 = {};
    j0.A = fcat; j0.lda = 384; j0.aoff = 0;
    j0.B1 = wb_kvR; j0.B2 = wb_qR; j0.b1rows = 384; j0.Nout = 576; j0.K = 192; j0.bStride = 0;
    j0.outH = (f16*)(ws + O_QKV0); j0.ldo = 576;
    j1 = j0;
    j1.aoff = 192; j1.B1 = wb_kvG; j1.B2 = wb_qG; j1.outH = (f16*)(ws + O_QKV1);
    j2.A = fcat; j2.lda = 384; j2.aoff = 0;
    j2.B1 = wb_g1; j2.B2 = wb_g1; j2.b1rows = 768; j2.Nout = 768; j2.K = 384; j2.bStride = 0;
    j2.bg1 = b_g1; j2.wg2 = w_g2; j2.alpha_acc = (float*)(ws + O_ALPHA);
    gemm_fused_kernel<<<4096, 256, 0, stream>>>(j0, j1, j2);
  }
  qk_transpose_kernel<<<dim3(64, 6, 4), 256, 0, stream>>>((const f16*)(ws + O_QKV0),
                                                          (const f16*)(ws + O_QKV1),
                                                          (f16*)(ws + O_QKT));
  gram_mfma_kernel<<<dim3(16, 8, 2), 256, 0, stream>>>((const f16*)(ws + O_QKT),
                                                       (float*)(ws + O_GRAM));
  softmax_kernel<<<16, 64, 0, stream>>>((const float*)(ws + O_GRAM), temp, (float*)(ws + O_ATT));
  mbuild_kernel<<<576, 256, 0, stream>>>(w_fc, (const float*)(ws + O_ATT), (f16*)(ws + O_MCAT));
  {  // ctx + fc + residual -> outpm fp32
    G2Args a = {};
    a.B1 = (const f16*)(ws + O_MCAT); a.B2 = (const f16*)(ws + O_MCAT);
    a.b1rows = 192; a.Nout = 192; a.K = 384; a.bStride = 73728;
    a.vraw = (const f16*)(ws + O_QKV0); a.vrgb = (const f16*)(ws + O_QKV1);
    a.alpha_pre = (float*)(ws + O_ALPHA); a.bg2 = b_g2;
    a.bfc = b_fc; a.fcat = fcat; a.outpm = (float*)(ws + O_OUTPM);
    gemm2_k<2><<<dim3(256, 2), 256, 0, stream>>>(a);
  }
  norm_pm_kernel<<<512, 256, 0, stream>>>((const float*)(ws + O_OUTPM), (f16*)(ws + O_NORM));
  {  // pin gemm -> hidden
    G2Args a = {};
    a.A = (const f16*)(ws + O_NORM); a.lda = 192; a.aoff = 0;
    a.B1 = wb_pin; a.B2 = wb_pin; a.b1rows = 1024; a.Nout = 1024; a.K = 192; a.bStride = 0;
    a.outH = (f16*)(ws + O_HID); a.ldo = 1024;
    gemm2_k<0><<<dim3(256, 8), 256, 0, stream>>>(a);
  }
  dwmish_kernel<<<dim3(64, 128, 2), 256, 0, stream>>>((const f16*)(ws + O_HID), w_dw5, w_dwd,
                                                      (f16*)(ws + O_U));
  {  // pout gemm + residual -> d_out (NCHW fp32)
    G2Args a = {};
    a.A = (const f16*)(ws + O_U); a.lda = 512; a.aoff = 0;
    a.B1 = wb_pout; a.B2 = wb_pout; a.b1rows = 192; a.Nout = 192; a.K = 512; a.bStride = 0;
    a.outpm_r = (const float*)(ws + O_OUTPM); a.dout = dout;
    gemm2_k<3><<<dim3(256, 2), 256, 0, stream>>>(a);
  }
}